// Round 8
// baseline (647.461 us; speedup 1.0000x reference)
//
#include <hip/hip_runtime.h>

typedef unsigned short ushort_t;
typedef unsigned int uint32;
typedef __bf16 bf16x8 __attribute__((ext_vector_type(8)));
typedef float f32x4 __attribute__((ext_vector_type(4)));

#define NTOK 128
#define DIMX 180
#define NH 6
#define HD 30
#define KP 192
#define NWIN 64
#define QTILES 4

__device__ __forceinline__ ushort_t f2bf(float f){
  uint32 u = __float_as_uint(f);
  u += 0x7FFFu + ((u >> 16) & 1u);
  return (ushort_t)(u >> 16);
}
__device__ __forceinline__ float bf2f(ushort_t h){
  return __uint_as_float(((uint32)h) << 16);
}
__device__ __forceinline__ f32x4 mfma16(bf16x8 a, bf16x8 b, f32x4 c){
  return __builtin_amdgcn_mfma_f32_16x16x32_bf16(a, b, c, 0, 0, 0);
}

// ---------------- prep kernels ----------------

// wqkvP fragment-contiguous: ((ct_g*6+ks)*64 + lane)*8 + e
__global__ void prep_wqkv(const float* __restrict__ w, ushort_t* __restrict__ o){
  int blk = blockIdx.x;               // ct_g*6 + ks, 216 blocks
  int ct_g = blk / 6, ks = blk - ct_g*6;
  int lane = threadIdx.x;             // 64
  int l16 = lane & 15, lq = lane >> 4;
  int oc = ct_g*16 + l16;
  int seg = oc >> 5, dd = oc & 31;
  int sel = seg / NH, head = seg % NH;
  ushort_t vals[8];
  #pragma unroll
  for (int e = 0; e < 8; e++){
    int k = ks*32 + lq*8 + e;
    float v = 0.f;
    if (dd < HD && k < DIMX) v = w[k*(3*DIMX) + sel*DIMX + head*HD + dd];
    vals[e] = f2bf(v);
  }
  *reinterpret_cast<uint4*>(&o[((size_t)blk*64 + lane)*8]) =
      *reinterpret_cast<const uint4*>(vals);
}

// wfcP fragment-contiguous, K padded per-head to 32
__global__ void prep_wfc(const float* __restrict__ w, ushort_t* __restrict__ o){
  int blk = blockIdx.x;               // ct_g*6 + ks, 72 blocks
  int ct_g = blk / 6, ks = blk - ct_g*6;
  int lane = threadIdx.x;
  int l16 = lane & 15, lq = lane >> 4;
  int oc = ct_g*16 + l16;
  ushort_t vals[8];
  #pragma unroll
  for (int e = 0; e < 8; e++){
    int k = ks*32 + lq*8 + e;
    int hh = k >> 5, d = k & 31;
    float v = (d < HD && oc < DIMX) ? w[(hh*HD + d)*DIMX + oc] : 0.f;
    vals[e] = f2bf(v);
  }
  *reinterpret_cast<uint4*>(&o[((size_t)blk*64 + lane)*8]) =
      *reinterpret_cast<const uint4*>(vals);
}

// bias_p in MFMA C-fragment order
__global__ void prep_bias(const float* __restrict__ rpt, const float* __restrict__ mask,
                          const int* __restrict__ rpi, ushort_t* __restrict__ o){
  int blk = blockIdx.x;            // (w*6+h)*8 + wave
  int wave = blk & 7, wh = blk >> 3;
  int h = wh % NH, w = wh / NH;
  int i = threadIdx.x;             // 512
  int lane = i >> 3, t = i & 7;
  int l16 = lane & 15, lq = lane >> 4;
  int m = t*16 + l16;
  ushort_t vals[4];
  #pragma unroll
  for (int r = 0; r < 4; r++){
    int n = wave*16 + lq*4 + r;
    float v = rpt[rpi[n*NTOK + m]*NH + h] + mask[((size_t)w*NTOK + n)*NTOK + m];
    vals[r] = f2bf(v);
  }
  *reinterpret_cast<uint2*>(&o[((size_t)blk*64 + lane)*32 + t*4]) =
      *reinterpret_cast<const uint2*>(vals);
}

// ---------------- QKV projection, software-pipelined over 4 tiles ----------------
// grid 512, 512 thr. Each block: 4 consecutive 64-row tiles.
// LDS 51200 B: xs [64][200] bf16; epilogue aliases: cqk [64][392], cv [192][72].
// Next tile's x prefetched to 6 float4 regs before MFMA (T14 issue-early/write-late).
__global__ __launch_bounds__(512, 4) void qkv_kernel(
    const float* __restrict__ x, const ushort_t* __restrict__ wqkvP,
    const float* __restrict__ b_qkv,
    ushort_t* __restrict__ Qo, ushort_t* __restrict__ Ko, ushort_t* __restrict__ Vo)
{
  __shared__ ushort_t sm1[25600];   // 51200 B
  ushort_t* xs  = sm1;            // [64][200]
  ushort_t* cqk = sm1;            // [64][392]  (pass A alias)
  ushort_t* cv  = sm1;            // [192][72]  (pass B alias)

  const int tid = threadIdx.x;
  const int wave = tid >> 6, lane = tid & 63;
  const int wm = wave >> 2, wn = wave & 3;
  const int l16 = lane & 15, lq = lane >> 4;
  const int t0 = blockIdx.x * QTILES;
  const float scale = 0.18257418583505536f;   // 1/sqrt(30)

  float4 pf[6];
  // prologue: load tile 0
  {
    const float* xb = x + (size_t)t0 * 64 * DIMX;
    #pragma unroll
    for (int j = 0; j < 6; j++){
      int c = j*512 + tid;
      if (c < 2880) pf[j] = reinterpret_cast<const float4*>(xb)[c];
    }
  }
  // write regs -> xs (+ zero pad cols)
  #pragma unroll
  for (int j = 0; j < 6; j++){
    int c = j*512 + tid;
    if (c < 2880){
      int row = c / 45, c4 = (c % 45) * 4;
      uint32 lo = ((uint32)f2bf(pf[j].y) << 16) | f2bf(pf[j].x);
      uint32 hi = ((uint32)f2bf(pf[j].w) << 16) | f2bf(pf[j].z);
      *reinterpret_cast<uint2*>(&xs[row*200 + c4]) = make_uint2(lo, hi);
    }
  }
  for (int c = tid; c < 64*12; c += 512)
    xs[(c/12)*200 + 180 + (c%12)] = 0;
  __syncthreads();

  for (int it = 0; it < QTILES; it++){
    const int tt = t0 + it;
    // issue-early: prefetch next tile's x to regs
    if (it + 1 < QTILES){
      const float* xb = x + (size_t)(tt+1) * 64 * DIMX;
      #pragma unroll
      for (int j = 0; j < 6; j++){
        int c = j*512 + tid;
        if (c < 2880) pf[j] = reinterpret_cast<const float4*>(xb)[c];
      }
    }

    f32x4 acc[2][9];
    #pragma unroll
    for (int i = 0; i < 2; i++)
      #pragma unroll
      for (int j = 0; j < 9; j++) acc[i][j] = f32x4{0.f,0.f,0.f,0.f};

    #pragma unroll
    for (int ks = 0; ks < 6; ks++){
      const int k0 = ks*32 + lq*8;
      bf16x8 a0 = *reinterpret_cast<const bf16x8*>(&xs[(wm*32 +      l16)*200 + k0]);
      bf16x8 a1 = *reinterpret_cast<const bf16x8*>(&xs[(wm*32 + 16 + l16)*200 + k0]);
      #pragma unroll
      for (int ct = 0; ct < 9; ct++){
        bf16x8 bw = *reinterpret_cast<const bf16x8*>(
            wqkvP + ((size_t)((wn*9 + ct)*6 + ks)*64 + lane)*8);   // contiguous 1KB/wave
        acc[0][ct] = mfma16(a0, bw, acc[0][ct]);
        acc[1][ct] = mfma16(a1, bw, acc[1][ct]);
      }
    }
    __syncthreads();   // xs reads done

    const int b = tt >> 1;
    const int half = tt & 1;

    // ---- pass A: Q,K -> cqk ----
    #pragma unroll
    for (int ct = 0; ct < 9; ct++){
      const int gt = wn*9 + ct;           // 0..35
      const int seg = gt >> 1;            // 0..17
      if (seg < 12){
        const int d = (gt & 1)*16 + l16;  // 0..31
        const int sel = seg / NH, hh = seg % NH;
        float bias = (d < HD) ? b_qkv[sel*DIMX + hh*HD + d] : 0.f;
        #pragma unroll
        for (int rt = 0; rt < 2; rt++){
          #pragma unroll
          for (int r = 0; r < 4; r++){
            const int row = wm*32 + rt*16 + lq*4 + r;
            float v = acc[rt][ct][r];
            if (d < HD) v += bias;
            if (sel == 0) v *= scale;
            cqk[row*392 + seg*32 + d] = f2bf(v);
          }
        }
      }
    }
    __syncthreads();
    for (int c = tid; c < 3072; c += 512){        // Q,K stores
      int s = c >> 8, rem = c & 255;
      int nl = rem >> 2, dc = rem & 3;
      bf16x8 vdat = *reinterpret_cast<const bf16x8*>(&cqk[nl*392 + s*32 + dc*8]);
      ushort_t* dst = (s < NH) ? Qo : Ko;
      int hh = (s < NH) ? s : s - NH;
      *reinterpret_cast<bf16x8*>(
        &dst[(((size_t)b*NH + hh)*NTOK + half*64 + nl)*32 + dc*8]) = vdat;
    }
    __syncthreads();   // cqk reads done

    // ---- pass B: V -> cv (transposed) ----
    #pragma unroll
    for (int ct = 0; ct < 9; ct++){
      const int gt = wn*9 + ct;
      const int seg = gt >> 1;
      if (seg >= 12){
        const int d = (gt & 1)*16 + l16;
        const int hh = seg - 12;
        float bias = (d < HD) ? b_qkv[2*DIMX + hh*HD + d] : 0.f;
        #pragma unroll
        for (int rt = 0; rt < 2; rt++){
          #pragma unroll
          for (int r = 0; r < 4; r++){
            const int row = wm*32 + rt*16 + lq*4 + r;
            float v = acc[rt][ct][r];
            if (d < HD) v += bias;
            cv[(hh*32 + d)*72 + row] = f2bf(v);
          }
        }
      }
    }
    __syncthreads();
    for (int c = tid; c < 1536; c += 512){        // V^T stores
      int vr = c >> 3, nc = c & 7;
      bf16x8 vdat = *reinterpret_cast<const bf16x8*>(&cv[vr*72 + nc*8]);
      *reinterpret_cast<bf16x8*>(
        &Vo[((size_t)b*192 + vr)*NTOK + half*64 + nc*8]) = vdat;
    }

    // write-late: next tile's x -> xs
    if (it + 1 < QTILES){
      __syncthreads();   // cv reads done, LDS free
      #pragma unroll
      for (int j = 0; j < 6; j++){
        int c = j*512 + tid;
        if (c < 2880){
          int row = c / 45, c4 = (c % 45) * 4;
          uint32 lo = ((uint32)f2bf(pf[j].y) << 16) | f2bf(pf[j].x);
          uint32 hi = ((uint32)f2bf(pf[j].w) << 16) | f2bf(pf[j].z);
          *reinterpret_cast<uint2*>(&xs[row*200 + c4]) = make_uint2(lo, hi);
        }
      }
      for (int c = tid; c < 64*12; c += 512)
        xs[(c/12)*200 + 180 + (c%12)] = 0;
      __syncthreads();
    }
  }
}

// ---------------- attention (no FC), double-buffered K/V, ao -> Ko region ----------------
// grid 1024, 512 thr, 8 waves x 16 q-rows. LDS 46080 B. (unchanged, proven)
__global__ __launch_bounds__(512, 4) void attn_kernel(
    const ushort_t* __restrict__ Qo, const ushort_t* __restrict__ Ko,
    const ushort_t* __restrict__ Vo, const ushort_t* __restrict__ bias_p,
    ushort_t* __restrict__ aoW)     // == Ko (head region reused after consumption)
{
  __shared__ ushort_t sm[23040];
  const int tid = threadIdx.x;
  const int b = blockIdx.x;
  const int wk = b & (NWIN-1);
  const int wave = tid >> 6, lane = tid & 63;
  const int l16 = lane & 15, lq = lane >> 4;
  const int wbase = wave * 16;
  const int krow = tid >> 2, kpart = tid & 3;
  const int vrow = tid >> 4, vpart = tid & 15;
  ushort_t* pw = sm + 17920 + wave*640;

  // head 0 staging
  *reinterpret_cast<bf16x8*>(&sm[krow*36 + kpart*8]) =
      *reinterpret_cast<const bf16x8*>(Ko + (size_t)b*NH*NTOK*32 + krow*32 + kpart*8);
  *reinterpret_cast<bf16x8*>(&sm[9216 + vrow*136 + vpart*8]) =
      *reinterpret_cast<const bf16x8*>(Vo + (size_t)b*NH*32*NTOK + vrow*NTOK + vpart*8);
  bf16x8 aq = *reinterpret_cast<const bf16x8*>(
      Qo + ((size_t)b*NH*NTOK + wbase + l16)*32 + lq*8);
  bf16x8 bb[4];
  {
    const ushort_t* bp = bias_p + (((size_t)wk*NH*8 + wave)*64 + lane)*32;
    #pragma unroll
    for (int c = 0; c < 4; c++) bb[c] = *reinterpret_cast<const bf16x8*>(bp + c*8);
  }
  __syncthreads();

  for (int h = 0; h < NH; h++){
    const int cur = h & 1;
    ushort_t* k_cur = sm + (cur ? 4608 : 0);
    ushort_t* v_cur = sm + 9216 + (cur ? 4352 : 0);
    ushort_t* k_nxt = sm + (cur ? 0 : 4608);
    ushort_t* v_nxt = sm + 9216 + (cur ? 0 : 4352);

    // prefetch next head (issue-early, write-late)
    bf16x8 kreg = {}, vreg = {}, aq_n = {};
    bf16x8 bbn[4] = {};
    if (h < NH-1){
      kreg = *reinterpret_cast<const bf16x8*>(
          Ko + ((size_t)b*NH + h+1)*NTOK*32 + krow*32 + kpart*8);
      vreg = *reinterpret_cast<const bf16x8*>(
          Vo + ((size_t)b*NH + h+1)*32*NTOK + vrow*NTOK + vpart*8);
      aq_n = *reinterpret_cast<const bf16x8*>(
          Qo + (((size_t)b*NH + h+1)*NTOK + wbase + l16)*32 + lq*8);
      const ushort_t* bp = bias_p + (((size_t)(wk*NH + h+1)*8 + wave)*64 + lane)*32;
      #pragma unroll
      for (int c = 0; c < 4; c++) bbn[c] = *reinterpret_cast<const bf16x8*>(bp + c*8);
    }

    // QK^T (scale folded into Q)
    f32x4 s[8];
    #pragma unroll
    for (int t = 0; t < 8; t++){
      bf16x8 bk = *reinterpret_cast<const bf16x8*>(&k_cur[(t*16 + l16)*36 + lq*8]);
      s[t] = mfma16(aq, bk, f32x4{0.f,0.f,0.f,0.f});
    }
    #pragma unroll
    for (int c = 0; c < 4; c++)
      #pragma unroll
      for (int r = 0; r < 4; r++){
        s[2*c][r]   += (float)bb[c][r];
        s[2*c+1][r] += (float)bb[c][4+r];
      }

    // wave-parallel softmax per row
    #pragma unroll
    for (int r = 0; r < 4; r++){
      float m = s[0][r];
      #pragma unroll
      for (int t = 1; t < 8; t++) m = fmaxf(m, s[t][r]);
      #pragma unroll
      for (int off = 1; off < 16; off <<= 1) m = fmaxf(m, __shfl_xor(m, off));
      float sum = 0.f;
      #pragma unroll
      for (int t = 0; t < 8; t++){
        float e = __expf(s[t][r] - m);
        s[t][r] = e; sum += e;
      }
      #pragma unroll
      for (int off = 1; off < 16; off <<= 1) sum += __shfl_xor(sum, off);
      float inv = 1.0f / sum;
      #pragma unroll
      for (int t = 0; t < 8; t++) s[t][r] *= inv;
    }

    // PV in 4 k-quarters via per-wave P buffer
    f32x4 po[2] = { f32x4{0.f,0.f,0.f,0.f}, f32x4{0.f,0.f,0.f,0.f} };
    #pragma unroll
    for (int q = 0; q < 4; q++){
      #pragma unroll
      for (int r = 0; r < 4; r++)
        #pragma unroll
        for (int t2 = 0; t2 < 2; t2++)
          pw[(lq*4 + r)*40 + t2*16 + l16] = f2bf(s[2*q + t2][r]);
      bf16x8 ap = *reinterpret_cast<const bf16x8*>(&pw[l16*40 + lq*8]);
      #pragma unroll
      for (int ct = 0; ct < 2; ct++){
        bf16x8 bv = *reinterpret_cast<const bf16x8*>(&v_cur[(ct*16 + l16)*136 + q*32 + lq*8]);
        po[ct] = mfma16(ap, bv, po[ct]);
      }
    }

    // po -> pw bounce -> coalesced 1KB/wave store into consumed Ko[b][h]
    #pragma unroll
    for (int ct = 0; ct < 2; ct++)
      #pragma unroll
      for (int r = 0; r < 4; r++)
        pw[(lq*4 + r)*40 + ct*16 + l16] = f2bf(po[ct][r]);   // cols 30/31 exact 0
    {
      bf16x8 vv = *reinterpret_cast<const bf16x8*>(&pw[(lane>>2)*40 + (lane&3)*8]);
      *reinterpret_cast<bf16x8*>(
        aoW + (((size_t)b*NH + h)*NTOK + wbase + (lane>>2))*32 + (lane&3)*8) = vv;
    }

    // write-late staging of next head
    if (h < NH-1){
      *reinterpret_cast<bf16x8*>(&k_nxt[krow*36 + kpart*8]) = kreg;
      *reinterpret_cast<bf16x8*>(&v_nxt[vrow*136 + vpart*8]) = vreg;
      aq = aq_n;
      #pragma unroll
      for (int c = 0; c < 4; c++) bb[c] = bbn[c];
    }
    __syncthreads();
  }
}

// ---------------- FC GEMM, software-pipelined over 4 tiles ----------------
// grid 512, 512 thr. aoP layout = Ko: [b][h][128][32].
// LDS 25600 B: xs [64][200] bf16; epilogue ob [32][180] f32 aliased, 2 half-passes.
__global__ __launch_bounds__(512, 4) void fc_kernel(
    const ushort_t* __restrict__ aoP, const ushort_t* __restrict__ wfcP,
    const float* __restrict__ b_fc, float* __restrict__ out)
{
  __shared__ ushort_t xs[64*200];   // 25600 B
  const int tid = threadIdx.x;
  const int wave = tid >> 6, lane = tid & 63;
  const int wm = wave >> 2, wn = wave & 3;
  const int l16 = lane & 15, lq = lane >> 4;
  const int t0 = blockIdx.x * QTILES;

  bf16x8 pf[3];
  // prologue: load tile 0 (aoP rows, packed [64][192] -> xs stride 200)
  {
    const int b = t0 >> 1, half = t0 & 1;
    #pragma unroll
    for (int j = 0; j < 3; j++){
      int c = j*512 + tid;
      int row = c / 24, t = c % 24;
      pf[j] = *reinterpret_cast<const bf16x8*>(
          aoP + (((size_t)b*NH + (t>>2))*NTOK + half*64 + row)*32 + (t&3)*8);
    }
  }
  #pragma unroll
  for (int j = 0; j < 3; j++){
    int c = j*512 + tid;
    int row = c / 24, t = c % 24;
    *reinterpret_cast<bf16x8*>(&xs[row*200 + t*8]) = pf[j];
  }
  __syncthreads();

  for (int it = 0; it < QTILES; it++){
    const int tt = t0 + it;
    // issue-early: prefetch next tile
    if (it + 1 < QTILES){
      const int bn = (tt+1) >> 1, halfn = (tt+1) & 1;
      #pragma unroll
      for (int j = 0; j < 3; j++){
        int c = j*512 + tid;
        int row = c / 24, t = c % 24;
        pf[j] = *reinterpret_cast<const bf16x8*>(
            aoP + (((size_t)bn*NH + (t>>2))*NTOK + halfn*64 + row)*32 + (t&3)*8);
      }
    }

    f32x4 acc[2][3];
    #pragma unroll
    for (int i = 0; i < 2; i++)
      #pragma unroll
      for (int j = 0; j < 3; j++) acc[i][j] = f32x4{0.f,0.f,0.f,0.f};

    #pragma unroll
    for (int ks = 0; ks < 6; ks++){
      const int k0 = ks*32 + lq*8;
      bf16x8 a0 = *reinterpret_cast<const bf16x8*>(&xs[(wm*32 +      l16)*200 + k0]);
      bf16x8 a1 = *reinterpret_cast<const bf16x8*>(&xs[(wm*32 + 16 + l16)*200 + k0]);
      #pragma unroll
      for (int ct = 0; ct < 3; ct++){
        bf16x8 bw = *reinterpret_cast<const bf16x8*>(
            wfcP + ((size_t)((wn*3 + ct)*6 + ks)*64 + lane)*8);
        acc[0][ct] = mfma16(a0, bw, acc[0][ct]);
        acc[1][ct] = mfma16(a1, bw, acc[1][ct]);
      }
    }

    // epilogue: two 32-row half-passes through fp32 bounce (aliases xs)
    float* ob = reinterpret_cast<float*>(xs);   // [32][180] f32 per pass
    for (int hp = 0; hp < 2; hp++){
      __syncthreads();   // xs GEMM reads done (hp=0) / prev half stores done
      if (wm == hp){
        #pragma unroll
        for (int ct = 0; ct < 3; ct++){
          const int col = (wn*3 + ct)*16 + l16;
          if (col < DIMX){
            const float bfc = b_fc[col];
            #pragma unroll
            for (int rt = 0; rt < 2; rt++)
              #pragma unroll
              for (int r = 0; r < 4; r++)
                ob[(rt*16 + lq*4 + r)*DIMX + col] = acc[rt][ct][r] + bfc;
          }
        }
      }
      __syncthreads();
      for (int c = tid; c < 1440; c += 512){
        int row = c / 45, cc = (c % 45)*4;
        float4 v = *reinterpret_cast<const float4*>(&ob[row*DIMX + cc]);
        *reinterpret_cast<float4*>(
            &out[((size_t)tt*64 + hp*32 + row)*DIMX + cc]) = v;
      }
    }

    // write-late: next tile -> xs
    if (it + 1 < QTILES){
      __syncthreads();   // ob reads done
      #pragma unroll
      for (int j = 0; j < 3; j++){
        int c = j*512 + tid;
        int row = c / 24, t = c % 24;
        *reinterpret_cast<bf16x8*>(&xs[row*200 + t*8]) = pf[j];
      }
      __syncthreads();
    }
  }
}

// ---------------- launch ----------------
extern "C" void kernel_launch(void* const* d_in, const int* in_sizes, int n_in,
                              void* d_out, int out_size, void* d_ws, size_t ws_size,
                              hipStream_t stream)
{
  const float* x      = (const float*)d_in[0];
  const float* w_qkv  = (const float*)d_in[1];
  const float* b_qkv  = (const float*)d_in[2];
  const float* w_fc   = (const float*)d_in[3];
  const float* b_fc   = (const float*)d_in[4];
  const float* rpt    = (const float*)d_in[5];
  const float* mask   = (const float*)d_in[6];
  const int*   rpi    = (const int*)d_in[7];
  float* out = (float*)d_out;

  char* ws = (char*)d_ws;
  // layout (bytes):
  //   0         wqkvP   216*64*8*2 = 221184
  //   221184    wfcP    72*64*8*2  = 73728
  //   294912    bias_p  12582912
  //   12877824  Qo      50331648
  //   63209472  Ko      50331648   (reused as attention-output aoP)
  //   113541120 Vo      50331648   -> total 163872768
  if (ws_size < (size_t)163872768) return;
  ushort_t* wqkvP  = (ushort_t*)(ws);
  ushort_t* wfcP   = (ushort_t*)(ws + 221184);
  ushort_t* bias_p = (ushort_t*)(ws + 294912);
  ushort_t* Qo     = (ushort_t*)(ws + 12877824);
  ushort_t* Ko     = (ushort_t*)(ws + 63209472);
  ushort_t* Vo     = (ushort_t*)(ws + 113541120);

  hipLaunchKernelGGL(prep_wqkv, dim3(216), dim3(64), 0, stream, w_qkv, wqkvP);
  hipLaunchKernelGGL(prep_wfc,  dim3(72),  dim3(64), 0, stream, w_fc, wfcP);
  hipLaunchKernelGGL(prep_bias, dim3(NWIN*NH*8), dim3(512), 0, stream, rpt, mask, rpi, bias_p);

  hipLaunchKernelGGL(qkv_kernel, dim3(512), dim3(512), 0, stream,
                     x, wqkvP, b_qkv, Qo, Ko, Vo);

  hipLaunchKernelGGL(attn_kernel, dim3(1024), dim3(512), 0, stream,
                     Qo, Ko, Vo, bias_p, Ko /*aoW*/);

  hipLaunchKernelGGL(fc_kernel, dim3(512), dim3(512), 0, stream,
                     Ko /*aoP*/, wfcP, b_fc, out);
}

// Round 9
// 270.842 us; speedup vs baseline: 2.3905x; 2.3905x over previous
//
#include <hip/hip_runtime.h>

typedef unsigned short ushort_t;
typedef unsigned int uint32;
typedef __bf16 bf16x8 __attribute__((ext_vector_type(8)));
typedef float f32x4 __attribute__((ext_vector_type(4)));

#define NTOK 128
#define DIMX 180
#define NH 6
#define HD 30
#define NWIN 64

__device__ __forceinline__ ushort_t f2bf(float f){
  uint32 u = __float_as_uint(f);
  u += 0x7FFFu + ((u >> 16) & 1u);
  return (ushort_t)(u >> 16);
}
__device__ __forceinline__ float bf2f(ushort_t h){
  return __uint_as_float(((uint32)h) << 16);
}
__device__ __forceinline__ f32x4 mfma16(bf16x8 a, bf16x8 b, f32x4 c){
  return __builtin_amdgcn_mfma_f32_16x16x32_bf16(a, b, c, 0, 0, 0);
}

// ---------------- prep kernels (unchanged, proven) ----------------

// wqkvP fragment-contiguous: ((ct_g*6+ks)*64 + lane)*8 + e
__global__ void prep_wqkv(const float* __restrict__ w, ushort_t* __restrict__ o){
  int blk = blockIdx.x;               // ct_g*6 + ks, 216 blocks
  int ct_g = blk / 6, ks = blk - ct_g*6;
  int lane = threadIdx.x;             // 64
  int l16 = lane & 15, lq = lane >> 4;
  int oc = ct_g*16 + l16;
  int seg = oc >> 5, dd = oc & 31;
  int sel = seg / NH, head = seg % NH;
  ushort_t vals[8];
  #pragma unroll
  for (int e = 0; e < 8; e++){
    int k = ks*32 + lq*8 + e;
    float v = 0.f;
    if (dd < HD && k < DIMX) v = w[k*(3*DIMX) + sel*DIMX + head*HD + dd];
    vals[e] = f2bf(v);
  }
  *reinterpret_cast<uint4*>(&o[((size_t)blk*64 + lane)*8]) =
      *reinterpret_cast<const uint4*>(vals);
}

// wfcP fragment-contiguous, K padded per-head to 32
__global__ void prep_wfc(const float* __restrict__ w, ushort_t* __restrict__ o){
  int blk = blockIdx.x;               // ct_g*6 + ks, 72 blocks
  int ct_g = blk / 6, ks = blk - ct_g*6;
  int lane = threadIdx.x;
  int l16 = lane & 15, lq = lane >> 4;
  int oc = ct_g*16 + l16;
  ushort_t vals[8];
  #pragma unroll
  for (int e = 0; e < 8; e++){
    int k = ks*32 + lq*8 + e;
    int hh = k >> 5, d = k & 31;
    float v = (d < HD && oc < DIMX) ? w[(hh*HD + d)*DIMX + oc] : 0.f;
    vals[e] = f2bf(v);
  }
  *reinterpret_cast<uint4*>(&o[((size_t)blk*64 + lane)*8]) =
      *reinterpret_cast<const uint4*>(vals);
}

// bias_p in MFMA C-fragment order
__global__ void prep_bias(const float* __restrict__ rpt, const float* __restrict__ mask,
                          const int* __restrict__ rpi, ushort_t* __restrict__ o){
  int blk = blockIdx.x;            // (w*6+h)*8 + wave
  int wave = blk & 7, wh = blk >> 3;
  int h = wh % NH, w = wh / NH;
  int i = threadIdx.x;             // 512
  int lane = i >> 3, t = i & 7;
  int l16 = lane & 15, lq = lane >> 4;
  int m = t*16 + l16;
  ushort_t vals[4];
  #pragma unroll
  for (int r = 0; r < 4; r++){
    int n = wave*16 + lq*4 + r;
    float v = rpt[rpi[n*NTOK + m]*NH + h] + mask[((size_t)w*NTOK + n)*NTOK + m];
    vals[r] = f2bf(v);
  }
  *reinterpret_cast<uint2*>(&o[((size_t)blk*64 + lane)*32 + t*4]) =
      *reinterpret_cast<const uint2*>(vals);
}

// ---------------- QKV projection: 256-thr blocks, 32x288 tiles ----------------
// grid 8192: bid = rt*2 + ch. rt = 32-row tile (0..4095), ch = column half.
// 4 waves: wm = wave>>1 (row 16-half), wn = wave&1 (col 144-half). acc[9] = 36 VGPR.
// LDS 18944 B: xs [32][200] (6400 ush) / cqk [32][296] (9472) / cv [192][40] (7680) aliased.
// Vo chunked layout: [b][h][rc][32d][32tok] (2KB full-line stores per head per block).
__global__ __launch_bounds__(256, 5) void qkv_kernel(
    const float* __restrict__ x, const ushort_t* __restrict__ wqkvP,
    const float* __restrict__ b_qkv,
    ushort_t* __restrict__ Qo, ushort_t* __restrict__ Ko, ushort_t* __restrict__ Vo)
{
  __shared__ ushort_t sm[9472];
  ushort_t* xs  = sm;   // [32][200]
  ushort_t* cqk = sm;   // [32][296]
  ushort_t* cv  = sm;   // [192][40]

  const int tid = threadIdx.x;
  const int rt = blockIdx.x >> 1;
  const int ch = blockIdx.x & 1;
  const int b = rt >> 2;             // window
  const int rowChunk = rt & 3;       // 32-token chunk within window

  // stage x: 32 x 180 fp32 -> bf16 [32][200], pad cols 180..191 = 0
  const float* xb = x + (size_t)rt * 32 * DIMX;
  for (int c = tid; c < 1440; c += 256){
    int row = c / 45, c4 = (c % 45) * 4;
    float4 f = reinterpret_cast<const float4*>(xb)[c];
    uint32 lo = ((uint32)f2bf(f.y) << 16) | f2bf(f.x);
    uint32 hi = ((uint32)f2bf(f.w) << 16) | f2bf(f.z);
    *reinterpret_cast<uint2*>(&xs[row*200 + c4]) = make_uint2(lo, hi);
  }
  for (int c = tid; c < 384; c += 256)
    xs[(c/12)*200 + 180 + (c%12)] = 0;
  __syncthreads();

  const int wave = tid >> 6, lane = tid & 63;
  const int wm = wave >> 1, wn = wave & 1;
  const int l16 = lane & 15, lq = lane >> 4;

  f32x4 acc[9];
  #pragma unroll
  for (int j = 0; j < 9; j++) acc[j] = f32x4{0.f,0.f,0.f,0.f};

  #pragma unroll
  for (int ks = 0; ks < 6; ks++){
    const int k0 = ks*32 + lq*8;
    bf16x8 a = *reinterpret_cast<const bf16x8*>(&xs[(wm*16 + l16)*200 + k0]);
    #pragma unroll
    for (int ct = 0; ct < 9; ct++){
      const int ct_g = ch*18 + wn*9 + ct;
      bf16x8 bw = *reinterpret_cast<const bf16x8*>(
          wqkvP + ((size_t)(ct_g*6 + ks)*64 + lane)*8);   // contiguous 1KB/wave
      acc[ct] = mfma16(a, bw, acc[ct]);
    }
  }
  __syncthreads();   // xs dead

  const float scale = 0.18257418583505536f;   // 1/sqrt(30)

  // ---- pass A: Q/K half-segs -> cqk [32][296] ----
  #pragma unroll
  for (int ct = 0; ct < 9; ct++){
    const int gt = wn*9 + ct;            // 0..17 local
    const int gseg = ch*9 + (gt >> 1);   // global seg 0..17
    if (gseg < 12){
      const int d = (gt & 1)*16 + l16;
      const int sel = gseg / NH, hh = gseg % NH;
      float bias = (d < HD) ? b_qkv[sel*DIMX + hh*HD + d] : 0.f;
      #pragma unroll
      for (int r = 0; r < 4; r++){
        const int row = wm*16 + lq*4 + r;
        float v = acc[ct][r];
        if (d < HD) v += bias;
        if (sel == 0) v *= scale;
        cqk[row*296 + (gt>>1)*32 + d] = f2bf(v);
      }
    }
  }
  __syncthreads();
  {
    const int nqk = ch ? 3 : 9;          // local qk segs
    for (int c = tid; c < nqk*128; c += 256){
      int s = c >> 7, rem = c & 127;
      int nl = rem >> 2, dc = rem & 3;
      bf16x8 vdat = *reinterpret_cast<const bf16x8*>(&cqk[nl*296 + s*32 + dc*8]);
      const int gseg = ch*9 + s;
      ushort_t* dst = (gseg < NH) ? Qo : Ko;
      const int hh = (gseg < NH) ? gseg : gseg - NH;
      *reinterpret_cast<bf16x8*>(
        &dst[(((size_t)b*NH + hh)*NTOK + rowChunk*32 + nl)*32 + dc*8]) = vdat;
    }
  }

  // ---- pass B: V -> cv [192][40] (transposed), ch==1 only ----
  if (ch == 1){
    __syncthreads();   // cqk reads done
    #pragma unroll
    for (int ct = 0; ct < 9; ct++){
      const int gt = wn*9 + ct;
      if (gt >= 6){                       // gseg >= 12
        const int d = (gt & 1)*16 + l16;
        const int hh = (gt >> 1) - 3;
        float bias = (d < HD) ? b_qkv[2*DIMX + hh*HD + d] : 0.f;
        #pragma unroll
        for (int r = 0; r < 4; r++){
          const int row = wm*16 + lq*4 + r;
          float v = acc[ct][r];
          if (d < HD) v += bias;
          cv[(hh*32 + d)*40 + row] = f2bf(v);
        }
      }
    }
    __syncthreads();
    for (int c = tid; c < 768; c += 256){  // 6 heads x 128 b128-chunks
      int hh = c >> 7, rem = c & 127;
      int d = rem >> 2, dc = rem & 3;
      bf16x8 vdat = *reinterpret_cast<const bf16x8*>(&cv[(hh*32 + d)*40 + dc*8]);
      *reinterpret_cast<bf16x8*>(
        &Vo[(((size_t)b*NH + hh)*4 + rowChunk)*1024 + d*32 + dc*8]) = vdat;
    }
  }
}

// ---------------- attention (round-7 structure; Vo addressing chunked) ----------------
// grid 1024, 512 thr, 8 waves x 16 q-rows. LDS 46080 B.
__global__ __launch_bounds__(512, 4) void attn_kernel(
    const ushort_t* __restrict__ Qo, const ushort_t* __restrict__ Ko,
    const ushort_t* __restrict__ Vo, const ushort_t* __restrict__ bias_p,
    ushort_t* __restrict__ aoW)     // == Ko (head region reused after consumption)
{
  __shared__ ushort_t sm[23040];
  const int tid = threadIdx.x;
  const int b = blockIdx.x;
  const int wk = b & (NWIN-1);
  const int wave = tid >> 6, lane = tid & 63;
  const int l16 = lane & 15, lq = lane >> 4;
  const int wbase = wave * 16;
  const int krow = tid >> 2, kpart = tid & 3;
  const int vrow = tid >> 4, vpart = tid & 15;    // vrow = d, vpart = token chunk
  const int vrc = vpart >> 2, vtr = (vpart & 3)*8;
  ushort_t* pw = sm + 17920 + wave*640;

  // head 0 staging
  *reinterpret_cast<bf16x8*>(&sm[krow*36 + kpart*8]) =
      *reinterpret_cast<const bf16x8*>(Ko + (size_t)b*NH*NTOK*32 + krow*32 + kpart*8);
  *reinterpret_cast<bf16x8*>(&sm[9216 + vrow*136 + vpart*8]) =
      *reinterpret_cast<const bf16x8*>(
          Vo + ((size_t)b*NH*4 + vrc)*1024 + vrow*32 + vtr);
  bf16x8 aq = *reinterpret_cast<const bf16x8*>(
      Qo + ((size_t)b*NH*NTOK + wbase + l16)*32 + lq*8);
  bf16x8 bb[4];
  {
    const ushort_t* bp = bias_p + (((size_t)wk*NH*8 + wave)*64 + lane)*32;
    #pragma unroll
    for (int c = 0; c < 4; c++) bb[c] = *reinterpret_cast<const bf16x8*>(bp + c*8);
  }
  __syncthreads();

  for (int h = 0; h < NH; h++){
    const int cur = h & 1;
    ushort_t* k_cur = sm + (cur ? 4608 : 0);
    ushort_t* v_cur = sm + 9216 + (cur ? 4352 : 0);
    ushort_t* k_nxt = sm + (cur ? 0 : 4608);
    ushort_t* v_nxt = sm + 9216 + (cur ? 0 : 4352);

    // prefetch next head (issue-early, write-late)
    bf16x8 kreg = {}, vreg = {}, aq_n = {};
    bf16x8 bbn[4] = {};
    if (h < NH-1){
      kreg = *reinterpret_cast<const bf16x8*>(
          Ko + ((size_t)b*NH + h+1)*NTOK*32 + krow*32 + kpart*8);
      vreg = *reinterpret_cast<const bf16x8*>(
          Vo + (((size_t)b*NH + h+1)*4 + vrc)*1024 + vrow*32 + vtr);
      aq_n = *reinterpret_cast<const bf16x8*>(
          Qo + (((size_t)b*NH + h+1)*NTOK + wbase + l16)*32 + lq*8);
      const ushort_t* bp = bias_p + (((size_t)(wk*NH + h+1)*8 + wave)*64 + lane)*32;
      #pragma unroll
      for (int c = 0; c < 4; c++) bbn[c] = *reinterpret_cast<const bf16x8*>(bp + c*8);
    }

    // QK^T (scale folded into Q)
    f32x4 s[8];
    #pragma unroll
    for (int t = 0; t < 8; t++){
      bf16x8 bk = *reinterpret_cast<const bf16x8*>(&k_cur[(t*16 + l16)*36 + lq*8]);
      s[t] = mfma16(aq, bk, f32x4{0.f,0.f,0.f,0.f});
    }
    #pragma unroll
    for (int c = 0; c < 4; c++)
      #pragma unroll
      for (int r = 0; r < 4; r++){
        s[2*c][r]   += (float)bb[c][r];
        s[2*c+1][r] += (float)bb[c][4+r];
      }

    // wave-parallel softmax per row
    #pragma unroll
    for (int r = 0; r < 4; r++){
      float m = s[0][r];
      #pragma unroll
      for (int t = 1; t < 8; t++) m = fmaxf(m, s[t][r]);
      #pragma unroll
      for (int off = 1; off < 16; off <<= 1) m = fmaxf(m, __shfl_xor(m, off));
      float sum = 0.f;
      #pragma unroll
      for (int t = 0; t < 8; t++){
        float e = __expf(s[t][r] - m);
        s[t][r] = e; sum += e;
      }
      #pragma unroll
      for (int off = 1; off < 16; off <<= 1) sum += __shfl_xor(sum, off);
      float inv = 1.0f / sum;
      #pragma unroll
      for (int t = 0; t < 8; t++) s[t][r] *= inv;
    }

    // PV in 4 k-quarters via per-wave P buffer
    f32x4 po[2] = { f32x4{0.f,0.f,0.f,0.f}, f32x4{0.f,0.f,0.f,0.f} };
    #pragma unroll
    for (int q = 0; q < 4; q++){
      #pragma unroll
      for (int r = 0; r < 4; r++)
        #pragma unroll
        for (int t2 = 0; t2 < 2; t2++)
          pw[(lq*4 + r)*40 + t2*16 + l16] = f2bf(s[2*q + t2][r]);
      bf16x8 ap = *reinterpret_cast<const bf16x8*>(&pw[l16*40 + lq*8]);
      #pragma unroll
      for (int ct = 0; ct < 2; ct++){
        bf16x8 bv = *reinterpret_cast<const bf16x8*>(&v_cur[(ct*16 + l16)*136 + q*32 + lq*8]);
        po[ct] = mfma16(ap, bv, po[ct]);
      }
    }

    // po -> pw bounce -> coalesced 1KB/wave store into consumed Ko[b][h]
    #pragma unroll
    for (int ct = 0; ct < 2; ct++)
      #pragma unroll
      for (int r = 0; r < 4; r++)
        pw[(lq*4 + r)*40 + ct*16 + l16] = f2bf(po[ct][r]);   // cols 30/31 exact 0
    {
      bf16x8 vv = *reinterpret_cast<const bf16x8*>(&pw[(lane>>2)*40 + (lane&3)*8]);
      *reinterpret_cast<bf16x8*>(
        aoW + (((size_t)b*NH + h)*NTOK + wbase + (lane>>2))*32 + (lane&3)*8) = vv;
    }

    // write-late staging of next head
    if (h < NH-1){
      *reinterpret_cast<bf16x8*>(&k_nxt[krow*36 + kpart*8]) = kreg;
      *reinterpret_cast<bf16x8*>(&v_nxt[vrow*136 + vpart*8]) = vreg;
      aq = aq_n;
      #pragma unroll
      for (int c = 0; c < 4; c++) bb[c] = bbn[c];
    }
    __syncthreads();
  }
}

// ---------------- FC GEMM (round-7 verbatim) ----------------
// grid 2048 (64 rows), 512 thr. aoP layout = Ko: [b][h][128][32].
__global__ __launch_bounds__(512, 4) void fc_kernel(
    const ushort_t* __restrict__ aoP, const ushort_t* __restrict__ wfcP,
    const float* __restrict__ b_fc, float* __restrict__ out)
{
  __shared__ ushort_t xs[64*200];   // 25600 B
  const int tid = threadIdx.x;
  const int blk = blockIdx.x;
  const int b = blk >> 1, half = blk & 1;

  for (int c = tid; c < 1536; c += 512){
    int row = c / 24, t = c % 24;
    int hh = t >> 2, dc = t & 3;
    *reinterpret_cast<bf16x8*>(&xs[row*200 + t*8]) =
      *reinterpret_cast<const bf16x8*>(
        aoP + (((size_t)b*NH + hh)*NTOK + half*64 + row)*32 + dc*8);
  }
  __syncthreads();

  const int wave = tid >> 6, lane = tid & 63;
  const int wm = wave >> 2, wn = wave & 3;
  const int l16 = lane & 15, lq = lane >> 4;

  f32x4 acc[2][3];
  #pragma unroll
  for (int i = 0; i < 2; i++)
    #pragma unroll
    for (int j = 0; j < 3; j++) acc[i][j] = f32x4{0.f,0.f,0.f,0.f};

  #pragma unroll
  for (int ks = 0; ks < 6; ks++){
    const int k0 = ks*32 + lq*8;
    bf16x8 a0 = *reinterpret_cast<const bf16x8*>(&xs[(wm*32 +      l16)*200 + k0]);
    bf16x8 a1 = *reinterpret_cast<const bf16x8*>(&xs[(wm*32 + 16 + l16)*200 + k0]);
    #pragma unroll
    for (int ct = 0; ct < 3; ct++){
      bf16x8 bw = *reinterpret_cast<const bf16x8*>(
          wfcP + ((size_t)((wn*3 + ct)*6 + ks)*64 + lane)*8);
      acc[0][ct] = mfma16(a0, bw, acc[0][ct]);
      acc[1][ct] = mfma16(a1, bw, acc[1][ct]);
    }
  }

  // epilogue: two 32-row half-passes through fp32 bounce (fits 25600 B)
  float* ob = reinterpret_cast<float*>(xs);   // [32][180] f32 per pass
  for (int hp = 0; hp < 2; hp++){
    __syncthreads();
    if (wm == hp){
      #pragma unroll
      for (int ct = 0; ct < 3; ct++){
        const int col = (wn*3 + ct)*16 + l16;
        if (col < DIMX){
          const float bfc = b_fc[col];
          #pragma unroll
          for (int rt = 0; rt < 2; rt++)
            #pragma unroll
            for (int r = 0; r < 4; r++)
              ob[(rt*16 + lq*4 + r)*DIMX + col] = acc[rt][ct][r] + bfc;
        }
      }
    }
    __syncthreads();
    for (int c = tid; c < 1440; c += 512){
      int row = c / 45, cc = (c % 45)*4;
      float4 v = *reinterpret_cast<const float4*>(&ob[row*DIMX + cc]);
      *reinterpret_cast<float4*>(
          &out[((size_t)blk*64 + hp*32 + row)*DIMX + cc]) = v;
    }
  }
}

// ---------------- launch ----------------
extern "C" void kernel_launch(void* const* d_in, const int* in_sizes, int n_in,
                              void* d_out, int out_size, void* d_ws, size_t ws_size,
                              hipStream_t stream)
{
  const float* x      = (const float*)d_in[0];
  const float* w_qkv  = (const float*)d_in[1];
  const float* b_qkv  = (const float*)d_in[2];
  const float* w_fc   = (const float*)d_in[3];
  const float* b_fc   = (const float*)d_in[4];
  const float* rpt    = (const float*)d_in[5];
  const float* mask   = (const float*)d_in[6];
  const int*   rpi    = (const int*)d_in[7];
  float* out = (float*)d_out;

  char* ws = (char*)d_ws;
  // layout (bytes):
  //   0         wqkvP   216*64*8*2 = 221184
  //   221184    wfcP    72*64*8*2  = 73728
  //   294912    bias_p  12582912
  //   12877824  Qo      50331648
  //   63209472  Ko      50331648   (reused as attention-output aoP)
  //   113541120 Vo      50331648   -> total 163872768
  if (ws_size < (size_t)163872768) return;
  ushort_t* wqkvP  = (ushort_t*)(ws);
  ushort_t* wfcP   = (ushort_t*)(ws + 221184);
  ushort_t* bias_p = (ushort_t*)(ws + 294912);
  ushort_t* Qo     = (ushort_t*)(ws + 12877824);
  ushort_t* Ko     = (ushort_t*)(ws + 63209472);
  ushort_t* Vo     = (ushort_t*)(ws + 113541120);

  hipLaunchKernelGGL(prep_wqkv, dim3(216), dim3(64), 0, stream, w_qkv, wqkvP);
  hipLaunchKernelGGL(prep_wfc,  dim3(72),  dim3(64), 0, stream, w_fc, wfcP);
  hipLaunchKernelGGL(prep_bias, dim3(NWIN*NH*8), dim3(512), 0, stream, rpt, mask, rpi, bias_p);

  hipLaunchKernelGGL(qkv_kernel, dim3(8192), dim3(256), 0, stream,
                     x, wqkvP, b_qkv, Qo, Ko, Vo);

  hipLaunchKernelGGL(attn_kernel, dim3(1024), dim3(512), 0, stream,
                     Qo, Ko, Vo, bias_p, Ko /*aoW*/);

  hipLaunchKernelGGL(fc_kernel, dim3(2048), dim3(512), 0, stream,
                     Ko /*aoP*/, wfcP, b_fc, out);
}

// Round 10
// 258.807 us; speedup vs baseline: 2.5017x; 1.0465x over previous
//
#include <hip/hip_runtime.h>

typedef unsigned short ushort_t;
typedef unsigned int uint32;
typedef __bf16 bf16x8 __attribute__((ext_vector_type(8)));
typedef float f32x4 __attribute__((ext_vector_type(4)));

#define NTOK 128
#define DIMX 180
#define NH 6
#define HD 30
#define NWIN 64
#define LOG2E 1.4426950408889634f

__device__ __forceinline__ ushort_t f2bf(float f){
  uint32 u = __float_as_uint(f);
  u += 0x7FFFu + ((u >> 16) & 1u);
  return (ushort_t)(u >> 16);
}
__device__ __forceinline__ float bf2f(ushort_t h){
  return __uint_as_float(((uint32)h) << 16);
}
__device__ __forceinline__ f32x4 mfma16(bf16x8 a, bf16x8 b, f32x4 c){
  return __builtin_amdgcn_mfma_f32_16x16x32_bf16(a, b, c, 0, 0, 0);
}

// ---------------- prep kernels ----------------

// wqkvP fragment-contiguous: ((ct_g*6+ks)*64 + lane)*8 + e
__global__ void prep_wqkv(const float* __restrict__ w, ushort_t* __restrict__ o){
  int blk = blockIdx.x;               // ct_g*6 + ks, 216 blocks
  int ct_g = blk / 6, ks = blk - ct_g*6;
  int lane = threadIdx.x;             // 64
  int l16 = lane & 15, lq = lane >> 4;
  int oc = ct_g*16 + l16;
  int seg = oc >> 5, dd = oc & 31;
  int sel = seg / NH, head = seg % NH;
  ushort_t vals[8];
  #pragma unroll
  for (int e = 0; e < 8; e++){
    int k = ks*32 + lq*8 + e;
    float v = 0.f;
    if (dd < HD && k < DIMX) v = w[k*(3*DIMX) + sel*DIMX + head*HD + dd];
    vals[e] = f2bf(v);
  }
  *reinterpret_cast<uint4*>(&o[((size_t)blk*64 + lane)*8]) =
      *reinterpret_cast<const uint4*>(vals);
}

// wfcP fragment-contiguous, K padded per-head to 32
__global__ void prep_wfc(const float* __restrict__ w, ushort_t* __restrict__ o){
  int blk = blockIdx.x;               // ct_g*6 + ks, 72 blocks
  int ct_g = blk / 6, ks = blk - ct_g*6;
  int lane = threadIdx.x;
  int l16 = lane & 15, lq = lane >> 4;
  int oc = ct_g*16 + l16;
  ushort_t vals[8];
  #pragma unroll
  for (int e = 0; e < 8; e++){
    int k = ks*32 + lq*8 + e;
    int hh = k >> 5, d = k & 31;
    float v = (d < HD && oc < DIMX) ? w[(hh*HD + d)*DIMX + oc] : 0.f;
    vals[e] = f2bf(v);
  }
  *reinterpret_cast<uint4*>(&o[((size_t)blk*64 + lane)*8]) =
      *reinterpret_cast<const uint4*>(vals);
}

// bias_p in MFMA C-fragment order, pre-multiplied by log2(e) for exp2 softmax
__global__ void prep_bias(const float* __restrict__ rpt, const float* __restrict__ mask,
                          const int* __restrict__ rpi, ushort_t* __restrict__ o){
  int blk = blockIdx.x;            // (w*6+h)*8 + wave
  int wave = blk & 7, wh = blk >> 3;
  int h = wh % NH, w = wh / NH;
  int i = threadIdx.x;             // 512
  int lane = i >> 3, t = i & 7;
  int l16 = lane & 15, lq = lane >> 4;
  int m = t*16 + l16;
  ushort_t vals[4];
  #pragma unroll
  for (int r = 0; r < 4; r++){
    int n = wave*16 + lq*4 + r;
    float v = rpt[rpi[n*NTOK + m]*NH + h] + mask[((size_t)w*NTOK + n)*NTOK + m];
    vals[r] = f2bf(v * LOG2E);
  }
  *reinterpret_cast<uint2*>(&o[((size_t)blk*64 + lane)*32 + t*4]) =
      *reinterpret_cast<const uint2*>(vals);
}

// ---------------- QKV projection (round-7 proven structure) ----------------
// grid 2048 (64 rows), 512 thr. LDS 51200 B: xs [64][200];
// epilogue two passes aliased into xs: pass A cqk [64][392], pass B cv [192][72].
// Q pre-scaled by (1/sqrt(hd))*log2(e) for exp2 softmax.
__global__ __launch_bounds__(512, 4) void qkv_kernel(
    const float* __restrict__ x, const ushort_t* __restrict__ wqkvP,
    const float* __restrict__ b_qkv,
    ushort_t* __restrict__ Qo, ushort_t* __restrict__ Ko, ushort_t* __restrict__ Vo)
{
  __shared__ ushort_t sm1[25600];   // 51200 B
  ushort_t* xs  = sm1;            // [64][200]
  ushort_t* cqk = sm1;            // [64][392]  (pass A alias)
  ushort_t* cv  = sm1;            // [192][72]  (pass B alias)

  const int tid = threadIdx.x;
  const float* xb = x + (size_t)blockIdx.x * 64 * DIMX;

  for (int c = tid; c < 64*45; c += 512){
    int row = c / 45, c4 = (c % 45) * 4;
    float4 f = reinterpret_cast<const float4*>(xb)[c];
    uint32 lo = ((uint32)f2bf(f.y) << 16) | f2bf(f.x);
    uint32 hi = ((uint32)f2bf(f.w) << 16) | f2bf(f.z);
    *reinterpret_cast<uint2*>(&xs[row*200 + c4]) = make_uint2(lo, hi);
  }
  for (int c = tid; c < 64*12; c += 512)
    xs[(c/12)*200 + 180 + (c%12)] = 0;
  __syncthreads();

  const int wave = tid >> 6, lane = tid & 63;
  const int wm = wave >> 2, wn = wave & 3;
  const int l16 = lane & 15, lq = lane >> 4;

  f32x4 acc[2][9];
  #pragma unroll
  for (int i = 0; i < 2; i++)
    #pragma unroll
    for (int j = 0; j < 9; j++) acc[i][j] = f32x4{0.f,0.f,0.f,0.f};

  #pragma unroll
  for (int ks = 0; ks < 6; ks++){
    const int k0 = ks*32 + lq*8;
    bf16x8 a0 = *reinterpret_cast<const bf16x8*>(&xs[(wm*32 +      l16)*200 + k0]);
    bf16x8 a1 = *reinterpret_cast<const bf16x8*>(&xs[(wm*32 + 16 + l16)*200 + k0]);
    #pragma unroll
    for (int ct = 0; ct < 9; ct++){
      bf16x8 bw = *reinterpret_cast<const bf16x8*>(
          wqkvP + ((size_t)((wn*9 + ct)*6 + ks)*64 + lane)*8);   // contiguous 1KB/wave
      acc[0][ct] = mfma16(a0, bw, acc[0][ct]);
      acc[1][ct] = mfma16(a1, bw, acc[1][ct]);
    }
  }
  __syncthreads();   // xs dead

  const int b = blockIdx.x >> 1;
  const int half = blockIdx.x & 1;
  const float scale = 0.18257418583505536f * LOG2E;   // 1/sqrt(30) * log2(e)

  // ---- pass A: Q,K -> cqk ----
  #pragma unroll
  for (int ct = 0; ct < 9; ct++){
    const int gt = wn*9 + ct;           // 0..35
    const int seg = gt >> 1;            // 0..17
    if (seg < 12){
      const int d = (gt & 1)*16 + l16;  // 0..31
      const int sel = seg / NH, hh = seg % NH;
      float bias = (d < HD) ? b_qkv[sel*DIMX + hh*HD + d] : 0.f;
      #pragma unroll
      for (int rt = 0; rt < 2; rt++){
        #pragma unroll
        for (int r = 0; r < 4; r++){
          const int row = wm*32 + rt*16 + lq*4 + r;
          float v = acc[rt][ct][r];
          if (d < HD) v += bias;
          if (sel == 0) v *= scale;
          cqk[row*392 + seg*32 + d] = f2bf(v);
        }
      }
    }
  }
  __syncthreads();
  for (int c = tid; c < 3072; c += 512){        // Q,K: 12 segs x 64 rows x 4 chunks
    int s = c >> 8, rem = c & 255;
    int nl = rem >> 2, dc = rem & 3;
    bf16x8 vdat = *reinterpret_cast<const bf16x8*>(&cqk[nl*392 + s*32 + dc*8]);
    ushort_t* dst = (s < NH) ? Qo : Ko;
    int hh = (s < NH) ? s : s - NH;
    *reinterpret_cast<bf16x8*>(
      &dst[(((size_t)b*NH + hh)*NTOK + half*64 + nl)*32 + dc*8]) = vdat;
  }
  __syncthreads();   // cqk reads done

  // ---- pass B: V -> cv (transposed) ----
  #pragma unroll
  for (int ct = 0; ct < 9; ct++){
    const int gt = wn*9 + ct;
    const int seg = gt >> 1;
    if (seg >= 12){
      const int d = (gt & 1)*16 + l16;
      const int hh = seg - 12;
      float bias = (d < HD) ? b_qkv[2*DIMX + hh*HD + d] : 0.f;
      #pragma unroll
      for (int rt = 0; rt < 2; rt++){
        #pragma unroll
        for (int r = 0; r < 4; r++){
          const int row = wm*32 + rt*16 + lq*4 + r;
          float v = acc[rt][ct][r];
          if (d < HD) v += bias;
          cv[(hh*32 + d)*72 + row] = f2bf(v);
        }
      }
    }
  }
  __syncthreads();
  for (int c = tid; c < 1536; c += 512){        // V^T: 192 rows x 8 chunks
    int vr = c >> 3, nc = c & 7;
    bf16x8 vdat = *reinterpret_cast<const bf16x8*>(&cv[vr*72 + nc*8]);
    *reinterpret_cast<bf16x8*>(
      &Vo[((size_t)b*192 + vr)*NTOK + half*64 + nc*8]) = vdat;
  }
}

// ---------------- fused attention + FC ----------------
// grid 1024, 512 thr, 8 waves x 16 q-rows. LDS 46080 B.
// Phase 1 (r7 attn): dbuf K/V, exp2 softmax, ao -> Ko region (L2-hot).
// Phase 2 (r7 fc body): two 64-row passes over the dead K/V/P LDS region.
__global__ __launch_bounds__(512, 4) void attn_kernel(
    const ushort_t* __restrict__ Qo, const ushort_t* __restrict__ Ko,
    const ushort_t* __restrict__ Vo, const ushort_t* __restrict__ bias_p,
    ushort_t* __restrict__ aoW,     // == Ko (head region reused after consumption)
    const ushort_t* __restrict__ wfcP, const float* __restrict__ b_fc,
    float* __restrict__ out)
{
  __shared__ ushort_t sm[23040];
  const int tid = threadIdx.x;
  const int b = blockIdx.x;
  const int wk = b & (NWIN-1);
  const int wave = tid >> 6, lane = tid & 63;
  const int l16 = lane & 15, lq = lane >> 4;
  const int wbase = wave * 16;
  const int krow = tid >> 2, kpart = tid & 3;
  const int vrow = tid >> 4, vpart = tid & 15;
  ushort_t* pw = sm + 17920 + wave*640;

  // head 0 staging
  *reinterpret_cast<bf16x8*>(&sm[krow*36 + kpart*8]) =
      *reinterpret_cast<const bf16x8*>(Ko + (size_t)b*NH*NTOK*32 + krow*32 + kpart*8);
  *reinterpret_cast<bf16x8*>(&sm[9216 + vrow*136 + vpart*8]) =
      *reinterpret_cast<const bf16x8*>(Vo + (size_t)b*NH*32*NTOK + vrow*NTOK + vpart*8);
  bf16x8 aq = *reinterpret_cast<const bf16x8*>(
      Qo + ((size_t)b*NH*NTOK + wbase + l16)*32 + lq*8);
  bf16x8 bb[4];
  {
    const ushort_t* bp = bias_p + (((size_t)wk*NH*8 + wave)*64 + lane)*32;
    #pragma unroll
    for (int c = 0; c < 4; c++) bb[c] = *reinterpret_cast<const bf16x8*>(bp + c*8);
  }
  __syncthreads();

  for (int h = 0; h < NH; h++){
    const int cur = h & 1;
    ushort_t* k_cur = sm + (cur ? 4608 : 0);
    ushort_t* v_cur = sm + 9216 + (cur ? 4352 : 0);
    ushort_t* k_nxt = sm + (cur ? 0 : 4608);
    ushort_t* v_nxt = sm + 9216 + (cur ? 0 : 4352);

    // prefetch next head (issue-early, write-late)
    bf16x8 kreg = {}, vreg = {}, aq_n = {};
    bf16x8 bbn[4] = {};
    if (h < NH-1){
      kreg = *reinterpret_cast<const bf16x8*>(
          Ko + ((size_t)b*NH + h+1)*NTOK*32 + krow*32 + kpart*8);
      vreg = *reinterpret_cast<const bf16x8*>(
          Vo + ((size_t)b*NH + h+1)*32*NTOK + vrow*NTOK + vpart*8);
      aq_n = *reinterpret_cast<const bf16x8*>(
          Qo + (((size_t)b*NH + h+1)*NTOK + wbase + l16)*32 + lq*8);
      const ushort_t* bp = bias_p + (((size_t)(wk*NH + h+1)*8 + wave)*64 + lane)*32;
      #pragma unroll
      for (int c = 0; c < 4; c++) bbn[c] = *reinterpret_cast<const bf16x8*>(bp + c*8);
    }

    // QK^T (scale*log2e folded into Q; bias pre-multiplied by log2e)
    f32x4 s[8];
    #pragma unroll
    for (int t = 0; t < 8; t++){
      bf16x8 bk = *reinterpret_cast<const bf16x8*>(&k_cur[(t*16 + l16)*36 + lq*8]);
      s[t] = mfma16(aq, bk, f32x4{0.f,0.f,0.f,0.f});
    }
    #pragma unroll
    for (int c = 0; c < 4; c++)
      #pragma unroll
      for (int r = 0; r < 4; r++){
        s[2*c][r]   += (float)bb[c][r];
        s[2*c+1][r] += (float)bb[c][4+r];
      }

    // wave-parallel softmax per row (base-2)
    #pragma unroll
    for (int r = 0; r < 4; r++){
      float m = s[0][r];
      #pragma unroll
      for (int t = 1; t < 8; t++) m = fmaxf(m, s[t][r]);
      #pragma unroll
      for (int off = 1; off < 16; off <<= 1) m = fmaxf(m, __shfl_xor(m, off));
      float sum = 0.f;
      #pragma unroll
      for (int t = 0; t < 8; t++){
        float e = __builtin_exp2f(s[t][r] - m);
        s[t][r] = e; sum += e;
      }
      #pragma unroll
      for (int off = 1; off < 16; off <<= 1) sum += __shfl_xor(sum, off);
      float inv = 1.0f / sum;
      #pragma unroll
      for (int t = 0; t < 8; t++) s[t][r] *= inv;
    }

    // PV in 4 k-quarters via per-wave P buffer
    f32x4 po[2] = { f32x4{0.f,0.f,0.f,0.f}, f32x4{0.f,0.f,0.f,0.f} };
    #pragma unroll
    for (int q = 0; q < 4; q++){
      #pragma unroll
      for (int r = 0; r < 4; r++)
        #pragma unroll
        for (int t2 = 0; t2 < 2; t2++)
          pw[(lq*4 + r)*40 + t2*16 + l16] = f2bf(s[2*q + t2][r]);
      bf16x8 ap = *reinterpret_cast<const bf16x8*>(&pw[l16*40 + lq*8]);
      #pragma unroll
      for (int ct = 0; ct < 2; ct++){
        bf16x8 bv = *reinterpret_cast<const bf16x8*>(&v_cur[(ct*16 + l16)*136 + q*32 + lq*8]);
        po[ct] = mfma16(ap, bv, po[ct]);
      }
    }

    // po -> pw bounce -> coalesced 1KB/wave store into consumed Ko[b][h]
    #pragma unroll
    for (int ct = 0; ct < 2; ct++)
      #pragma unroll
      for (int r = 0; r < 4; r++)
        pw[(lq*4 + r)*40 + ct*16 + l16] = f2bf(po[ct][r]);   // cols 30/31 exact 0
    {
      bf16x8 vv = *reinterpret_cast<const bf16x8*>(&pw[(lane>>2)*40 + (lane&3)*8]);
      *reinterpret_cast<bf16x8*>(
        aoW + (((size_t)b*NH + h)*NTOK + wbase + (lane>>2))*32 + (lane&3)*8) = vv;
    }

    // write-late staging of next head
    if (h < NH-1){
      *reinterpret_cast<bf16x8*>(&k_nxt[krow*36 + kpart*8]) = kreg;
      *reinterpret_cast<bf16x8*>(&v_nxt[vrow*136 + vpart*8]) = vreg;
      aq = aq_n;
      #pragma unroll
      for (int c = 0; c < 4; c++) bb[c] = bbn[c];
    }
    __syncthreads();   // also drains aoW stores (vmcnt(0) before barrier)
  }

  // ---- phase 2: FC for this block's 128 rows (two 64-row passes) ----
  // K/V/P LDS dead; reuse sm as xs [64][200] (12800 ush) + ob [32][180] f32.
  ushort_t* xs = sm;
  const int wm = wave >> 2, wn = wave & 3;

  for (int pass = 0; pass < 2; pass++){
    if (pass) __syncthreads();           // prev pass's ob reads done
    for (int c = tid; c < 1536; c += 512){
      int row = c / 24, t = c % 24;
      int hh = t >> 2, dc = t & 3;
      *reinterpret_cast<bf16x8*>(&xs[row*200 + t*8]) =
        *reinterpret_cast<const bf16x8*>(
          aoW + (((size_t)b*NH + hh)*NTOK + pass*64 + row)*32 + dc*8);
    }
    __syncthreads();

    f32x4 acc[2][3];
    #pragma unroll
    for (int i = 0; i < 2; i++)
      #pragma unroll
      for (int j = 0; j < 3; j++) acc[i][j] = f32x4{0.f,0.f,0.f,0.f};

    #pragma unroll
    for (int ks = 0; ks < 6; ks++){
      const int k0 = ks*32 + lq*8;
      bf16x8 a0 = *reinterpret_cast<const bf16x8*>(&xs[(wm*32 +      l16)*200 + k0]);
      bf16x8 a1 = *reinterpret_cast<const bf16x8*>(&xs[(wm*32 + 16 + l16)*200 + k0]);
      #pragma unroll
      for (int ct = 0; ct < 3; ct++){
        bf16x8 bw = *reinterpret_cast<const bf16x8*>(
            wfcP + ((size_t)((wn*3 + ct)*6 + ks)*64 + lane)*8);
        acc[0][ct] = mfma16(a0, bw, acc[0][ct]);
        acc[1][ct] = mfma16(a1, bw, acc[1][ct]);
      }
    }

    // epilogue: two 32-row half-passes through fp32 bounce (aliases xs)
    float* ob = reinterpret_cast<float*>(xs);   // [32][180] f32 per pass
    for (int hp = 0; hp < 2; hp++){
      __syncthreads();   // xs GEMM reads done (hp=0) / prev half stores done
      if (wm == hp){
        #pragma unroll
        for (int ct = 0; ct < 3; ct++){
          const int col = (wn*3 + ct)*16 + l16;
          if (col < DIMX){
            const float bfc = b_fc[col];
            #pragma unroll
            for (int rt = 0; rt < 2; rt++)
              #pragma unroll
              for (int r = 0; r < 4; r++)
                ob[(rt*16 + lq*4 + r)*DIMX + col] = acc[rt][ct][r] + bfc;
          }
        }
      }
      __syncthreads();
      for (int c = tid; c < 1440; c += 512){
        int row = c / 45, cc = (c % 45)*4;
        float4 v = *reinterpret_cast<const float4*>(&ob[row*DIMX + cc]);
        *reinterpret_cast<float4*>(
            &out[((size_t)(b*2 + pass)*64 + hp*32 + row)*DIMX + cc]) = v;
      }
    }
  }
}

// ---------------- launch ----------------
extern "C" void kernel_launch(void* const* d_in, const int* in_sizes, int n_in,
                              void* d_out, int out_size, void* d_ws, size_t ws_size,
                              hipStream_t stream)
{
  const float* x      = (const float*)d_in[0];
  const float* w_qkv  = (const float*)d_in[1];
  const float* b_qkv  = (const float*)d_in[2];
  const float* w_fc   = (const float*)d_in[3];
  const float* b_fc   = (const float*)d_in[4];
  const float* rpt    = (const float*)d_in[5];
  const float* mask   = (const float*)d_in[6];
  const int*   rpi    = (const int*)d_in[7];
  float* out = (float*)d_out;

  char* ws = (char*)d_ws;
  // layout (bytes):
  //   0         wqkvP   216*64*8*2 = 221184
  //   221184    wfcP    72*64*8*2  = 73728
  //   294912    bias_p  12582912
  //   12877824  Qo      50331648
  //   63209472  Ko      50331648   (reused as attention-output aoP)
  //   113541120 Vo      50331648   -> total 163872768
  if (ws_size < (size_t)163872768) return;
  ushort_t* wqkvP  = (ushort_t*)(ws);
  ushort_t* wfcP   = (ushort_t*)(ws + 221184);
  ushort_t* bias_p = (ushort_t*)(ws + 294912);
  ushort_t* Qo     = (ushort_t*)(ws + 12877824);
  ushort_t* Ko     = (ushort_t*)(ws + 63209472);
  ushort_t* Vo     = (ushort_t*)(ws + 113541120);

  hipLaunchKernelGGL(prep_wqkv, dim3(216), dim3(64), 0, stream, w_qkv, wqkvP);
  hipLaunchKernelGGL(prep_wfc,  dim3(72),  dim3(64), 0, stream, w_fc, wfcP);
  hipLaunchKernelGGL(prep_bias, dim3(NWIN*NH*8), dim3(512), 0, stream, rpt, mask, rpi, bias_p);

  hipLaunchKernelGGL(qkv_kernel, dim3(2048), dim3(512), 0, stream,
                     x, wqkvP, b_qkv, Qo, Ko, Vo);

  hipLaunchKernelGGL(attn_kernel, dim3(1024), dim3(512), 0, stream,
                     Qo, Ko, Vo, bias_p, Ko /*aoW*/, wfcP, b_fc, out);
}

// Round 11
// 241.083 us; speedup vs baseline: 2.6856x; 1.0735x over previous
//
#include <hip/hip_runtime.h>

typedef unsigned short ushort_t;
typedef unsigned int uint32;
typedef __bf16 bf16x8 __attribute__((ext_vector_type(8)));
typedef float f32x4 __attribute__((ext_vector_type(4)));

#define NTOK 128
#define DIMX 180
#define NH 6
#define HD 30
#define NWIN 64
#define LOG2E 1.4426950408889634f
#define QSCALE (0.18257418583505536f * LOG2E)   // 1/sqrt(30) * log2(e)

__device__ __forceinline__ ushort_t f2bf(float f){
  uint32 u = __float_as_uint(f);
  u += 0x7FFFu + ((u >> 16) & 1u);
  return (ushort_t)(u >> 16);
}
__device__ __forceinline__ uint32 cvt_pk_bf16(float lo, float hi){
  uint32 r;
  asm("v_cvt_pk_bf16_f32 %0, %1, %2" : "=v"(r) : "v"(lo), "v"(hi));
  return r;
}
__device__ __forceinline__ f32x4 mfma16(bf16x8 a, bf16x8 b, f32x4 c){
  return __builtin_amdgcn_mfma_f32_16x16x32_bf16(a, b, c, 0, 0, 0);
}

// ---------------- prep kernels ----------------

// wqkvP fragment-contiguous: ((ct_g*6+ks)*64 + lane)*8 + e ; Q-segment pre-scaled
__global__ void prep_wqkv(const float* __restrict__ w, ushort_t* __restrict__ o){
  int blk = blockIdx.x;               // ct_g*6 + ks, 216 blocks
  int ct_g = blk / 6, ks = blk - ct_g*6;
  int lane = threadIdx.x;             // 64
  int l16 = lane & 15, lq = lane >> 4;
  int oc = ct_g*16 + l16;
  int seg = oc >> 5, dd = oc & 31;
  int sel = seg / NH, head = seg % NH;
  ushort_t vals[8];
  #pragma unroll
  for (int e = 0; e < 8; e++){
    int k = ks*32 + lq*8 + e;
    float v = 0.f;
    if (dd < HD && k < DIMX) v = w[k*(3*DIMX) + sel*DIMX + head*HD + dd];
    if (sel == 0) v *= QSCALE;
    vals[e] = f2bf(v);
  }
  *reinterpret_cast<uint4*>(&o[((size_t)blk*64 + lane)*8]) =
      *reinterpret_cast<const uint4*>(vals);
}

// wfcP fragment-contiguous; K positions pair-interleaved to match aoW layout:
// pos p in [0,32) holds original d = (p>>1) + (p&1)*16
__global__ void prep_wfc(const float* __restrict__ w, ushort_t* __restrict__ o){
  int blk = blockIdx.x;               // ct_g*6 + ks, 72 blocks
  int ct_g = blk / 6, ks = blk - ct_g*6;
  int lane = threadIdx.x;
  int l16 = lane & 15, lq = lane >> 4;
  int oc = ct_g*16 + l16;
  ushort_t vals[8];
  #pragma unroll
  for (int e = 0; e < 8; e++){
    int k = ks*32 + lq*8 + e;
    int hh = k >> 5, pos = k & 31;
    int d = (pos >> 1) + (pos & 1)*16;
    float v = (d < HD && oc < DIMX) ? w[(hh*HD + d)*DIMX + oc] : 0.f;
    vals[e] = f2bf(v);
  }
  *reinterpret_cast<uint4*>(&o[((size_t)blk*64 + lane)*8]) =
      *reinterpret_cast<const uint4*>(vals);
}

// bias_p in MFMA C-fragment order, pre-multiplied by log2(e) (exp2 softmax)
__global__ void prep_bias(const float* __restrict__ rpt, const float* __restrict__ mask,
                          const int* __restrict__ rpi, ushort_t* __restrict__ o){
  int blk = blockIdx.x;            // (w*6+h)*8 + wave
  int wave = blk & 7, wh = blk >> 3;
  int h = wh % NH, w = wh / NH;
  int i = threadIdx.x;             // 512
  int lane = i >> 3, t = i & 7;
  int l16 = lane & 15, lq = lane >> 4;
  int m = t*16 + l16;
  ushort_t vals[4];
  #pragma unroll
  for (int r = 0; r < 4; r++){
    int n = wave*16 + lq*4 + r;
    float v = rpt[rpi[n*NTOK + m]*NH + h] + mask[((size_t)w*NTOK + n)*NTOK + m];
    vals[r] = f2bf(v * LOG2E);
  }
  *reinterpret_cast<uint2*>(&o[((size_t)blk*64 + lane)*32 + t*4]) =
      *reinterpret_cast<const uint2*>(vals);
}

// ---------------- QKV projection (r7 structure; bias via C-init, V tokens interleaved) ----------------
// grid 2048 (64 rows), 512 thr. LDS 51200 B: xs [64][200];
// epilogue passes aliased: pass A cqk [64][392], pass B cv [192][72].
__global__ __launch_bounds__(512, 4) void qkv_kernel(
    const float* __restrict__ x, const ushort_t* __restrict__ wqkvP,
    const float* __restrict__ b_qkv,
    ushort_t* __restrict__ Qo, ushort_t* __restrict__ Ko, ushort_t* __restrict__ Vo)
{
  __shared__ ushort_t sm1[25600];   // 51200 B
  ushort_t* xs  = sm1;            // [64][200]
  ushort_t* cqk = sm1;            // [64][392]  (pass A alias)
  ushort_t* cv  = sm1;            // [192][72]  (pass B alias)

  const int tid = threadIdx.x;
  const float* xb = x + (size_t)blockIdx.x * 64 * DIMX;

  for (int c = tid; c < 64*45; c += 512){
    int row = c / 45, c4 = (c % 45) * 4;
    float4 f = reinterpret_cast<const float4*>(xb)[c];
    uint32 lo = ((uint32)f2bf(f.y) << 16) | f2bf(f.x);
    uint32 hi = ((uint32)f2bf(f.w) << 16) | f2bf(f.z);
    *reinterpret_cast<uint2*>(&xs[row*200 + c4]) = make_uint2(lo, hi);
  }
  for (int c = tid; c < 64*12; c += 512)
    xs[(c/12)*200 + 180 + (c%12)] = 0;

  const int wave = tid >> 6, lane = tid & 63;
  const int wm = wave >> 2, wn = wave & 3;
  const int l16 = lane & 15, lq = lane >> 4;

  // accumulators C-initialized with bias (Q-bias pre-scaled)
  f32x4 acc[2][9];
  #pragma unroll
  for (int ct = 0; ct < 9; ct++){
    const int gt = wn*9 + ct, seg = gt >> 1;
    const int d = (gt & 1)*16 + l16;
    const int sel = seg / NH, hh = seg % NH;
    float bc = 0.f;
    if (d < HD) bc = b_qkv[sel*DIMX + hh*HD + d];
    if (sel == 0) bc *= QSCALE;
    acc[0][ct] = f32x4{bc, bc, bc, bc};
    acc[1][ct] = acc[0][ct];
  }
  __syncthreads();

  #pragma unroll
  for (int ks = 0; ks < 6; ks++){
    const int k0 = ks*32 + lq*8;
    bf16x8 a0 = *reinterpret_cast<const bf16x8*>(&xs[(wm*32 +      l16)*200 + k0]);
    bf16x8 a1 = *reinterpret_cast<const bf16x8*>(&xs[(wm*32 + 16 + l16)*200 + k0]);
    #pragma unroll
    for (int ct = 0; ct < 9; ct++){
      bf16x8 bw = *reinterpret_cast<const bf16x8*>(
          wqkvP + ((size_t)((wn*9 + ct)*6 + ks)*64 + lane)*8);   // contiguous 1KB/wave
      acc[0][ct] = mfma16(a0, bw, acc[0][ct]);
      acc[1][ct] = mfma16(a1, bw, acc[1][ct]);
    }
  }
  __syncthreads();   // xs dead

  const int b = blockIdx.x >> 1;
  const int half = blockIdx.x & 1;

  // ---- pass A: Q,K -> cqk ----
  #pragma unroll
  for (int ct = 0; ct < 9; ct++){
    const int gt = wn*9 + ct;           // 0..35
    const int seg = gt >> 1;            // 0..17
    if (seg < 12){
      const int d = (gt & 1)*16 + l16;  // 0..31
      #pragma unroll
      for (int rt = 0; rt < 2; rt++){
        #pragma unroll
        for (int r = 0; r < 4; r++){
          const int row = wm*32 + rt*16 + lq*4 + r;
          cqk[row*392 + seg*32 + d] = f2bf(acc[rt][ct][r]);
        }
      }
    }
  }
  __syncthreads();
  for (int c = tid; c < 3072; c += 512){        // Q,K: 12 segs x 64 rows x 4 chunks
    int s = c >> 8, rem = c & 255;
    int nl = rem >> 2, dc = rem & 3;
    bf16x8 vdat = *reinterpret_cast<const bf16x8*>(&cqk[nl*392 + s*32 + dc*8]);
    ushort_t* dst = (s < NH) ? Qo : Ko;
    int hh = (s < NH) ? s : s - NH;
    *reinterpret_cast<bf16x8*>(
      &dst[(((size_t)b*NH + hh)*NTOK + half*64 + nl)*32 + dc*8]) = vdat;
  }
  __syncthreads();   // cqk reads done

  // ---- pass B: V -> cv (transposed; token cols pair-interleaved per 32-quarter) ----
  #pragma unroll
  for (int ct = 0; ct < 9; ct++){
    const int gt = wn*9 + ct;
    const int seg = gt >> 1;
    if (seg >= 12){
      const int d = (gt & 1)*16 + l16;
      const int hh = seg - 12;
      #pragma unroll
      for (int r = 0; r < 4; r++){
        const int row = wm*32 + (gt & 1)*0 + ((wn*9+ct)&0, 0) + 0;  // placeholder removed below
        (void)row;
      }
      #pragma unroll
      for (int rt = 0; rt < 2; rt++){
        #pragma unroll
        for (int r = 0; r < 4; r++){
          const int tok = wm*32 + rt*16 + lq*4 + r;          // 0..63
          const int tp = (tok & 32) + ((tok & 15) << 1) + ((tok >> 4) & 1);
          cv[(hh*32 + d)*72 + tp] = f2bf(acc[rt][ct][r]);
        }
      }
    }
  }
  __syncthreads();
  for (int c = tid; c < 1536; c += 512){        // V^T: 192 rows x 8 chunks
    int vr = c >> 3, nc = c & 7;
    bf16x8 vdat = *reinterpret_cast<const bf16x8*>(&cv[vr*72 + nc*8]);
    *reinterpret_cast<bf16x8*>(
      &Vo[((size_t)b*192 + vr)*NTOK + half*64 + nc*8]) = vdat;
  }
}

// ---------------- fused attention + FC ----------------
// grid 1024, 512 thr, 8 waves x 16 q-rows. LDS 46080 B.
__global__ __launch_bounds__(512, 4) void attn_kernel(
    const ushort_t* __restrict__ Qo, const ushort_t* __restrict__ Ko,
    const ushort_t* __restrict__ Vo, const ushort_t* __restrict__ bias_p,
    ushort_t* __restrict__ aoW,     // == Ko (head region reused after consumption)
    const ushort_t* __restrict__ wfcP, const float* __restrict__ b_fc,
    float* __restrict__ out)
{
  __shared__ ushort_t sm[23040];
  const int tid = threadIdx.x;
  const int b = blockIdx.x;
  const int wk = b & (NWIN-1);
  const int wave = tid >> 6, lane = tid & 63;
  const int l16 = lane & 15, lq = lane >> 4;
  const int wbase = wave * 16;
  const int krow = tid >> 2, kpart = tid & 3;
  const int vrow = tid >> 4, vpart = tid & 15;
  ushort_t* pw = sm + 17920 + wave*640;
  uint32*   pwu = reinterpret_cast<uint32*>(pw);

  // head 0 staging
  *reinterpret_cast<bf16x8*>(&sm[krow*36 + kpart*8]) =
      *reinterpret_cast<const bf16x8*>(Ko + (size_t)b*NH*NTOK*32 + krow*32 + kpart*8);
  *reinterpret_cast<bf16x8*>(&sm[9216 + vrow*136 + vpart*8]) =
      *reinterpret_cast<const bf16x8*>(Vo + (size_t)b*NH*32*NTOK + vrow*NTOK + vpart*8);
  bf16x8 aq = *reinterpret_cast<const bf16x8*>(
      Qo + ((size_t)b*NH*NTOK + wbase + l16)*32 + lq*8);
  bf16x8 bb[4];
  {
    const ushort_t* bp = bias_p + (((size_t)wk*NH*8 + wave)*64 + lane)*32;
    #pragma unroll
    for (int c = 0; c < 4; c++) bb[c] = *reinterpret_cast<const bf16x8*>(bp + c*8);
  }
  __syncthreads();

  for (int h = 0; h < NH; h++){
    const int cur = h & 1;
    ushort_t* k_cur = sm + (cur ? 4608 : 0);
    ushort_t* v_cur = sm + 9216 + (cur ? 4352 : 0);
    ushort_t* k_nxt = sm + (cur ? 0 : 4608);
    ushort_t* v_nxt = sm + 9216 + (cur ? 0 : 4352);

    // prefetch next head (issue-early, write-late)
    bf16x8 kreg = {}, vreg = {}, aq_n = {};
    bf16x8 bbn[4] = {};
    if (h < NH-1){
      kreg = *reinterpret_cast<const bf16x8*>(
          Ko + ((size_t)b*NH + h+1)*NTOK*32 + krow*32 + kpart*8);
      vreg = *reinterpret_cast<const bf16x8*>(
          Vo + ((size_t)b*NH + h+1)*32*NTOK + vrow*NTOK + vpart*8);
      aq_n = *reinterpret_cast<const bf16x8*>(
          Qo + (((size_t)b*NH + h+1)*NTOK + wbase + l16)*32 + lq*8);
      const ushort_t* bp = bias_p + (((size_t)(wk*NH + h+1)*8 + wave)*64 + lane)*32;
      #pragma unroll
      for (int c = 0; c < 4; c++) bbn[c] = *reinterpret_cast<const bf16x8*>(bp + c*8);
    }

    // QK^T with bias as accumulator C-init (bias & Q pre-scaled by log2e)
    f32x4 s[8];
    #pragma unroll
    for (int c = 0; c < 4; c++)
      #pragma unroll
      for (int r = 0; r < 4; r++){
        s[2*c][r]   = (float)bb[c][r];
        s[2*c+1][r] = (float)bb[c][4+r];
      }
    #pragma unroll
    for (int t = 0; t < 8; t++){
      bf16x8 bk = *reinterpret_cast<const bf16x8*>(&k_cur[(t*16 + l16)*36 + lq*8]);
      s[t] = mfma16(aq, bk, s[t]);
    }

    // softmax: exp2 direct (no max-sub; logits bounded), normalize deferred to po
    float inv[4];
    #pragma unroll
    for (int r = 0; r < 4; r++){
      float sum = 0.f;
      #pragma unroll
      for (int t = 0; t < 8; t++){
        float e = __builtin_exp2f(s[t][r]);
        s[t][r] = e; sum += e;
      }
      #pragma unroll
      for (int off = 1; off < 16; off <<= 1) sum += __shfl_xor(sum, off);
      inv[r] = __builtin_amdgcn_rcpf(sum);
    }

    // PV in 4 k-quarters; P packed via cvt_pk into pair-interleaved token layout
    f32x4 po[2] = { f32x4{0.f,0.f,0.f,0.f}, f32x4{0.f,0.f,0.f,0.f} };
    #pragma unroll
    for (int q = 0; q < 4; q++){
      #pragma unroll
      for (int r = 0; r < 4; r++)
        pwu[(lq*4 + r)*20 + l16] = cvt_pk_bf16(s[2*q][r], s[2*q+1][r]);
      bf16x8 ap = *reinterpret_cast<const bf16x8*>(&pw[l16*40 + lq*8]);
      #pragma unroll
      for (int ct = 0; ct < 2; ct++){
        bf16x8 bv = *reinterpret_cast<const bf16x8*>(&v_cur[(ct*16 + l16)*136 + q*32 + lq*8]);
        po[ct] = mfma16(ap, bv, po[ct]);
      }
    }

    // normalize + pack po (d pair-interleaved) -> pw -> coalesced 1KB/wave store
    #pragma unroll
    for (int r = 0; r < 4; r++)
      pwu[(lq*4 + r)*20 + l16] = cvt_pk_bf16(po[0][r]*inv[r], po[1][r]*inv[r]);
    {
      bf16x8 vv = *reinterpret_cast<const bf16x8*>(&pw[(lane>>2)*40 + (lane&3)*8]);
      *reinterpret_cast<bf16x8*>(
        aoW + (((size_t)b*NH + h)*NTOK + wbase + (lane>>2))*32 + (lane&3)*8) = vv;
    }

    // write-late staging of next head
    if (h < NH-1){
      *reinterpret_cast<bf16x8*>(&k_nxt[krow*36 + kpart*8]) = kreg;
      *reinterpret_cast<bf16x8*>(&v_nxt[vrow*136 + vpart*8]) = vreg;
      aq = aq_n;
      #pragma unroll
      for (int c = 0; c < 4; c++) bb[c] = bbn[c];
    }
    __syncthreads();
  }

  // ---- phase 2: FC for this block's 128 rows (two 64-row passes) ----
  ushort_t* xs = sm;
  const int wm = wave >> 2, wn = wave & 3;

  for (int pass = 0; pass < 2; pass++){
    if (pass) __syncthreads();
    for (int c = tid; c < 1536; c += 512){
      int row = c / 24, t = c % 24;
      int hh = t >> 2, dc = t & 3;
      *reinterpret_cast<bf16x8*>(&xs[row*200 + t*8]) =
        *reinterpret_cast<const bf16x8*>(
          aoW + (((size_t)b*NH + hh)*NTOK + pass*64 + row)*32 + dc*8);
    }
    __syncthreads();

    f32x4 acc[2][3];
    #pragma unroll
    for (int ct = 0; ct < 3; ct++){
      const int col = (wn*3 + ct)*16 + l16;
      float bfc = (col < DIMX) ? b_fc[col] : 0.f;
      acc[0][ct] = f32x4{bfc, bfc, bfc, bfc};
      acc[1][ct] = acc[0][ct];
    }

    #pragma unroll
    for (int ks = 0; ks < 6; ks++){
      const int k0 = ks*32 + lq*8;
      bf16x8 a0 = *reinterpret_cast<const bf16x8*>(&xs[(wm*32 +      l16)*200 + k0]);
      bf16x8 a1 = *reinterpret_cast<const bf16x8*>(&xs[(wm*32 + 16 + l16)*200 + k0]);
      #pragma unroll
      for (int ct = 0; ct < 3; ct++){
        bf16x8 bw = *reinterpret_cast<const bf16x8*>(
            wfcP + ((size_t)((wn*3 + ct)*6 + ks)*64 + lane)*8);
        acc[0][ct] = mfma16(a0, bw, acc[0][ct]);
        acc[1][ct] = mfma16(a1, bw, acc[1][ct]);
      }
    }

    // epilogue: two 32-row half-passes through fp32 bounce (aliases xs)
    float* ob = reinterpret_cast<float*>(xs);   // [32][180] f32 per pass
    for (int hp = 0; hp < 2; hp++){
      __syncthreads();
      if (wm == hp){
        #pragma unroll
        for (int ct = 0; ct < 3; ct++){
          const int col = (wn*3 + ct)*16 + l16;
          if (col < DIMX){
            #pragma unroll
            for (int rt = 0; rt < 2; rt++)
              #pragma unroll
              for (int r = 0; r < 4; r++)
                ob[(rt*16 + lq*4 + r)*DIMX + col] = acc[rt][ct][r];
          }
        }
      }
      __syncthreads();
      for (int c = tid; c < 1440; c += 512){
        int row = c / 45, cc = (c % 45)*4;
        float4 v = *reinterpret_cast<const float4*>(&ob[row*DIMX + cc]);
        *reinterpret_cast<float4*>(
            &out[((size_t)(b*2 + pass)*64 + hp*32 + row)*DIMX + cc]) = v;
      }
    }
  }
}

// ---------------- launch ----------------
extern "C" void kernel_launch(void* const* d_in, const int* in_sizes, int n_in,
                              void* d_out, int out_size, void* d_ws, size_t ws_size,
                              hipStream_t stream)
{
  const float* x      = (const float*)d_in[0];
  const float* w_qkv  = (const float*)d_in[1];
  const float* b_qkv  = (const float*)d_in[2];
  const float* w_fc   = (const float*)d_in[3];
  const float* b_fc   = (const float*)d_in[4];
  const float* rpt    = (const float*)d_in[5];
  const float* mask   = (const float*)d_in[6];
  const int*   rpi    = (const int*)d_in[7];
  float* out = (float*)d_out;

  char* ws = (char*)d_ws;
  // layout (bytes):
  //   0         wqkvP   216*64*8*2 = 221184
  //   221184    wfcP    72*64*8*2  = 73728
  //   294912    bias_p  12582912
  //   12877824  Qo      50331648
  //   63209472  Ko      50331648   (reused as attention-output aoP)
  //   113541120 Vo      50331648   -> total 163872768
  if (ws_size < (size_t)163872768) return;
  ushort_t* wqkvP  = (ushort_t*)(ws);
  ushort_t* wfcP   = (ushort_t*)(ws + 221184);
  ushort_t* bias_p = (ushort_t*)(ws + 294912);
  ushort_t* Qo     = (ushort_t*)(ws + 12877824);
  ushort_t* Ko     = (ushort_t*)(ws + 63209472);
  ushort_t* Vo     = (ushort_t*)(ws + 113541120);

  hipLaunchKernelGGL(prep_wqkv, dim3(216), dim3(64), 0, stream, w_qkv, wqkvP);
  hipLaunchKernelGGL(prep_wfc,  dim3(72),  dim3(64), 0, stream, w_fc, wfcP);
  hipLaunchKernelGGL(prep_bias, dim3(NWIN*NH*8), dim3(512), 0, stream, rpt, mask, rpi, bias_p);

  hipLaunchKernelGGL(qkv_kernel, dim3(2048), dim3(512), 0, stream,
                     x, wqkvP, b_qkv, Qo, Ko, Vo);

  hipLaunchKernelGGL(attn_kernel, dim3(1024), dim3(512), 0, stream,
                     Qo, Ko, Vo, bias_p, Ko /*aoW*/, wfcP, b_fc, out);
}

// Round 12
// 180.013 us; speedup vs baseline: 3.5967x; 1.3393x over previous
//
#include <hip/hip_runtime.h>

typedef unsigned short ushort_t;
typedef unsigned int uint32;
typedef __bf16 bf16x8 __attribute__((ext_vector_type(8)));
typedef float f32x4 __attribute__((ext_vector_type(4)));

#define NTOK 128
#define DIMX 180
#define NH 6
#define HD 30
#define NWIN 64
#define LOG2E 1.4426950408889634f
#define QSCALE (0.18257418583505536f * LOG2E)   // 1/sqrt(30) * log2(e)

__device__ __forceinline__ ushort_t f2bf(float f){
  uint32 u = __float_as_uint(f);
  u += 0x7FFFu + ((u >> 16) & 1u);
  return (ushort_t)(u >> 16);
}
__device__ __forceinline__ uint32 cvt_pk_bf16(float lo, float hi){
  uint32 r;
  asm("v_cvt_pk_bf16_f32 %0, %1, %2" : "=v"(r) : "v"(lo), "v"(hi));
  return r;
}
__device__ __forceinline__ f32x4 mfma16(bf16x8 a, bf16x8 b, f32x4 c){
  return __builtin_amdgcn_mfma_f32_16x16x32_bf16(a, b, c, 0, 0, 0);
}

// ---------------- prep kernels (r11 verbatim) ----------------

// wqkvP fragment-contiguous: ((ct_g*6+ks)*64 + lane)*8 + e ; Q-segment pre-scaled
__global__ void prep_wqkv(const float* __restrict__ w, ushort_t* __restrict__ o){
  int blk = blockIdx.x;               // ct_g*6 + ks, 216 blocks
  int ct_g = blk / 6, ks = blk - ct_g*6;
  int lane = threadIdx.x;             // 64
  int l16 = lane & 15, lq = lane >> 4;
  int oc = ct_g*16 + l16;
  int seg = oc >> 5, dd = oc & 31;
  int sel = seg / NH, head = seg % NH;
  ushort_t vals[8];
  #pragma unroll
  for (int e = 0; e < 8; e++){
    int k = ks*32 + lq*8 + e;
    float v = 0.f;
    if (dd < HD && k < DIMX) v = w[k*(3*DIMX) + sel*DIMX + head*HD + dd];
    if (sel == 0) v *= QSCALE;
    vals[e] = f2bf(v);
  }
  *reinterpret_cast<uint4*>(&o[((size_t)blk*64 + lane)*8]) =
      *reinterpret_cast<const uint4*>(vals);
}

// wfcP fragment-contiguous; K positions pair-interleaved to match aoW layout:
// pos p in [0,32) holds original d = (p>>1) + (p&1)*16
__global__ void prep_wfc(const float* __restrict__ w, ushort_t* __restrict__ o){
  int blk = blockIdx.x;               // ct_g*6 + ks, 72 blocks
  int ct_g = blk / 6, ks = blk - ct_g*6;
  int lane = threadIdx.x;
  int l16 = lane & 15, lq = lane >> 4;
  int oc = ct_g*16 + l16;
  ushort_t vals[8];
  #pragma unroll
  for (int e = 0; e < 8; e++){
    int k = ks*32 + lq*8 + e;
    int hh = k >> 5, pos = k & 31;
    int d = (pos >> 1) + (pos & 1)*16;
    float v = (d < HD && oc < DIMX) ? w[(hh*HD + d)*DIMX + oc] : 0.f;
    vals[e] = f2bf(v);
  }
  *reinterpret_cast<uint4*>(&o[((size_t)blk*64 + lane)*8]) =
      *reinterpret_cast<const uint4*>(vals);
}

// bias_p in MFMA C-fragment order, pre-multiplied by log2(e)
__global__ void prep_bias(const float* __restrict__ rpt, const float* __restrict__ mask,
                          const int* __restrict__ rpi, ushort_t* __restrict__ o){
  int blk = blockIdx.x;            // (w*6+h)*8 + wave
  int wave = blk & 7, wh = blk >> 3;
  int h = wh % NH, w = wh / NH;
  int i = threadIdx.x;             // 512
  int lane = i >> 3, t = i & 7;
  int l16 = lane & 15, lq = lane >> 4;
  int m = t*16 + l16;
  ushort_t vals[4];
  #pragma unroll
  for (int r = 0; r < 4; r++){
    int n = wave*16 + lq*4 + r;
    float v = rpt[rpi[n*NTOK + m]*NH + h] + mask[((size_t)w*NTOK + n)*NTOK + m];
    vals[r] = f2bf(v * LOG2E);
  }
  *reinterpret_cast<uint2*>(&o[((size_t)blk*64 + lane)*32 + t*4]) =
      *reinterpret_cast<const uint2*>(vals);
}

// ---------------- fully fused: QKV + attention + FC, one block per window ----------------
// grid 1024, 512 thr, 8 waves x 16 token-rows each.
// LDS 65024 B: ws [2304*8]=18432 ush @0 (head-h weight slice; FC reuses as xs/ob);
//   k_s [128][36]=4608 @18432; v_s [32][136]=4352 @23040; p_s 8x[16][40]=5120 @27392.
// x lives in registers (xf[6] bf16x8 per wave = its 16 rows, K padded to 192).
__global__ __launch_bounds__(512, 4) void fused_kernel(
    const float* __restrict__ x, const ushort_t* __restrict__ wqkvP,
    const float* __restrict__ b_qkv, const ushort_t* __restrict__ bias_p,
    ushort_t* __restrict__ aoW, const ushort_t* __restrict__ wfcP,
    const float* __restrict__ b_fc, float* __restrict__ out)
{
  __shared__ ushort_t sm[32512];
  ushort_t* ws  = sm;            // [6ct][6ks][64 lane][8]
  ushort_t* k_s = sm + 18432;    // [128 tok][36]
  ushort_t* v_s = sm + 23040;    // [32 d][136]  (token pos pair-interleaved)
  ushort_t* p_s = sm + 27392;    // 8 x [16][40]

  const int tid = threadIdx.x;
  const int b = blockIdx.x;
  const int wk = b & (NWIN-1);
  const int wave = tid >> 6, lane = tid & 63;
  const int l16 = lane & 15, lq = lane >> 4;
  const int wbase = wave * 16;
  ushort_t* pw = p_s + wave*640;
  uint32*   pwu = reinterpret_cast<uint32*>(pw);

  // ---- load this wave's 16 x-rows into bf16 register fragments (once) ----
  bf16x8 xf[6];
  {
    const float* xr = x + ((size_t)b*NTOK + wbase + l16)*DIMX;
    #pragma unroll
    for (int ks = 0; ks < 6; ks++){
      const int k0 = ks*32 + lq*8;
      float4 fa = {0.f,0.f,0.f,0.f}, fb = {0.f,0.f,0.f,0.f};
      if (k0 < DIMX)     fa = *reinterpret_cast<const float4*>(xr + k0);
      if (k0 + 4 < DIMX) fb = *reinterpret_cast<const float4*>(xr + k0 + 4);
      uint4 uu = { cvt_pk_bf16(fa.x, fa.y), cvt_pk_bf16(fa.z, fa.w),
                   cvt_pk_bf16(fb.x, fb.y), cvt_pk_bf16(fb.z, fb.w) };
      xf[ks] = *reinterpret_cast<bf16x8*>(&uu);
    }
  }

  for (int h = 0; h < NH; h++){
    // ---- stage head-h weight slice -> ws (coalesced), load bias frag ----
    bf16x8 bb[4];
    {
      const ushort_t* bp = bias_p + (((size_t)(wk*NH + h)*8 + wave)*64 + lane)*32;
      #pragma unroll
      for (int c = 0; c < 4; c++) bb[c] = *reinterpret_cast<const bf16x8*>(bp + c*8);
    }
    #pragma unroll
    for (int j = 0; j < 5; j++){
      int c = j*512 + tid;                 // (ct*6+ks)*64 + lane2, 2304 total
      if (c < 2304){
        int ct = c / 384, rem = c - ct*384;
        int ct_g = ((ct >> 1)*6 + h)*2 + (ct & 1);
        *reinterpret_cast<uint4*>(&ws[c*8]) =
            *reinterpret_cast<const uint4*>(&wqkvP[((size_t)ct_g*384 + rem)*8]);
      }
    }
    // QKV accumulators C-initialized with bias (Q pre-scaled)
    f32x4 acc[6];
    #pragma unroll
    for (int ct = 0; ct < 6; ct++){
      const int sel = ct >> 1;
      const int d = (ct & 1)*16 + l16;
      float bc = (d < HD) ? b_qkv[sel*DIMX + h*HD + d] : 0.f;
      if (sel == 0) bc *= QSCALE;
      acc[ct] = f32x4{bc, bc, bc, bc};
    }
    __syncthreads();   // ws ready; prev head's k_s/v_s/pw reads done

    // ---- QKV for head h: 16 rows x {Q,K,V}x32 per wave ----
    #pragma unroll
    for (int ks = 0; ks < 6; ks++){
      #pragma unroll
      for (int ct = 0; ct < 6; ct++){
        bf16x8 bw = *reinterpret_cast<const bf16x8*>(&ws[((ct*6 + ks)*64 + lane)*8]);
        acc[ct] = mfma16(xf[ks], bw, acc[ct]);
      }
    }

    // ---- epilogue: Q -> pw, K -> k_s, V -> v_s (interleaved token pos) ----
    #pragma unroll
    for (int hf = 0; hf < 2; hf++){
      const int d = hf*16 + l16;
      #pragma unroll
      for (int r = 0; r < 4; r++){
        const int tok = wbase + lq*4 + r;
        pw[(lq*4 + r)*40 + d] = f2bf(acc[0 + hf][r]);          // Q (own rows)
        k_s[tok*36 + d]       = f2bf(acc[2 + hf][r]);          // K
        const int tp = (tok & 96) + ((tok & 15) << 1) + ((tok >> 4) & 1);
        v_s[d*136 + tp]       = f2bf(acc[4 + hf][r]);          // V^T
      }
    }
    __syncthreads();   // k_s, v_s visible to all waves

    // ---- QK^T with bias C-init ----
    bf16x8 aq = *reinterpret_cast<const bf16x8*>(&pw[l16*40 + lq*8]);
    f32x4 s[8];
    #pragma unroll
    for (int c = 0; c < 4; c++)
      #pragma unroll
      for (int r = 0; r < 4; r++){
        s[2*c][r]   = (float)bb[c][r];
        s[2*c+1][r] = (float)bb[c][4+r];
      }
    #pragma unroll
    for (int t = 0; t < 8; t++){
      bf16x8 bk = *reinterpret_cast<const bf16x8*>(&k_s[(t*16 + l16)*36 + lq*8]);
      s[t] = mfma16(aq, bk, s[t]);
    }

    // ---- softmax: exp2 direct, deferred normalization ----
    float inv[4];
    #pragma unroll
    for (int r = 0; r < 4; r++){
      float sum = 0.f;
      #pragma unroll
      for (int t = 0; t < 8; t++){
        float e = __builtin_exp2f(s[t][r]);
        s[t][r] = e; sum += e;
      }
      #pragma unroll
      for (int off = 1; off < 16; off <<= 1) sum += __shfl_xor(sum, off);
      inv[r] = __builtin_amdgcn_rcpf(sum);
    }

    // ---- PV in 4 k-quarters; P packed via cvt_pk (pair-interleaved tokens) ----
    f32x4 po[2] = { f32x4{0.f,0.f,0.f,0.f}, f32x4{0.f,0.f,0.f,0.f} };
    #pragma unroll
    for (int q = 0; q < 4; q++){
      #pragma unroll
      for (int r = 0; r < 4; r++)
        pwu[(lq*4 + r)*20 + l16] = cvt_pk_bf16(s[2*q][r], s[2*q+1][r]);
      bf16x8 ap = *reinterpret_cast<const bf16x8*>(&pw[l16*40 + lq*8]);
      #pragma unroll
      for (int ct = 0; ct < 2; ct++){
        bf16x8 bv = *reinterpret_cast<const bf16x8*>(&v_s[(ct*16 + l16)*136 + q*32 + lq*8]);
        po[ct] = mfma16(ap, bv, po[ct]);
      }
    }

    // normalize + pack po (d pair-interleaved) -> pw -> coalesced 1KB/wave store
    #pragma unroll
    for (int r = 0; r < 4; r++)
      pwu[(lq*4 + r)*20 + l16] = cvt_pk_bf16(po[0][r]*inv[r], po[1][r]*inv[r]);
    {
      bf16x8 vv = *reinterpret_cast<const bf16x8*>(&pw[(lane>>2)*40 + (lane&3)*8]);
      *reinterpret_cast<bf16x8*>(
        aoW + (((size_t)b*NH + h)*NTOK + wbase + (lane>>2))*32 + (lane&3)*8) = vv;
    }
  }

  // ---- phase 2: FC for this block's 128 rows (two 64-row passes) ----
  __syncthreads();                 // drain aoW stores; all LDS reads done
  ushort_t* xs = sm;               // reuse ws region: [64][200] = 12800 ush
  const int wm = wave >> 2, wn = wave & 3;

  for (int pass = 0; pass < 2; pass++){
    if (pass) __syncthreads();
    for (int c = tid; c < 1536; c += 512){
      int row = c / 24, t = c % 24;
      *reinterpret_cast<bf16x8*>(&xs[row*200 + t*8]) =
        *reinterpret_cast<const bf16x8*>(
          aoW + (((size_t)b*NH + (t>>2))*NTOK + pass*64 + row)*32 + (t&3)*8);
    }
    __syncthreads();

    f32x4 acc2[2][3];
    #pragma unroll
    for (int ct = 0; ct < 3; ct++){
      const int col = (wn*3 + ct)*16 + l16;
      float bfc = (col < DIMX) ? b_fc[col] : 0.f;
      acc2[0][ct] = f32x4{bfc, bfc, bfc, bfc};
      acc2[1][ct] = acc2[0][ct];
    }

    #pragma unroll
    for (int ks = 0; ks < 6; ks++){
      const int k0 = ks*32 + lq*8;
      bf16x8 a0 = *reinterpret_cast<const bf16x8*>(&xs[(wm*32 +      l16)*200 + k0]);
      bf16x8 a1 = *reinterpret_cast<const bf16x8*>(&xs[(wm*32 + 16 + l16)*200 + k0]);
      #pragma unroll
      for (int ct = 0; ct < 3; ct++){
        bf16x8 bw = *reinterpret_cast<const bf16x8*>(
            wfcP + ((size_t)((wn*3 + ct)*6 + ks)*64 + lane)*8);
        acc2[0][ct] = mfma16(a0, bw, acc2[0][ct]);
        acc2[1][ct] = mfma16(a1, bw, acc2[1][ct]);
      }
    }

    // epilogue: two 32-row half-passes through fp32 bounce (aliases xs)
    float* ob = reinterpret_cast<float*>(xs);   // [32][180] f32 per pass
    for (int hp = 0; hp < 2; hp++){
      __syncthreads();
      if (wm == hp){
        #pragma unroll
        for (int ct = 0; ct < 3; ct++){
          const int col = (wn*3 + ct)*16 + l16;
          if (col < DIMX){
            #pragma unroll
            for (int rt = 0; rt < 2; rt++)
              #pragma unroll
              for (int r = 0; r < 4; r++)
                ob[(rt*16 + lq*4 + r)*DIMX + col] = acc2[rt][ct][r];
          }
        }
      }
      __syncthreads();
      for (int c = tid; c < 1440; c += 512){
        int row = c / 45, cc = (c % 45)*4;
        float4 v = *reinterpret_cast<const float4*>(&ob[row*DIMX + cc]);
        *reinterpret_cast<float4*>(
            &out[((size_t)(b*2 + pass)*64 + hp*32 + row)*DIMX + cc]) = v;
      }
    }
  }
}

// ---------------- launch ----------------
extern "C" void kernel_launch(void* const* d_in, const int* in_sizes, int n_in,
                              void* d_out, int out_size, void* d_ws, size_t ws_size,
                              hipStream_t stream)
{
  const float* x      = (const float*)d_in[0];
  const float* w_qkv  = (const float*)d_in[1];
  const float* b_qkv  = (const float*)d_in[2];
  const float* w_fc   = (const float*)d_in[3];
  const float* b_fc   = (const float*)d_in[4];
  const float* rpt    = (const float*)d_in[5];
  const float* mask   = (const float*)d_in[6];
  const int*   rpi    = (const int*)d_in[7];
  float* out = (float*)d_out;

  char* ws = (char*)d_ws;
  // layout (bytes):
  //   0         wqkvP   216*64*8*2 = 221184
  //   221184    wfcP    72*64*8*2  = 73728
  //   294912    bias_p  12582912
  //   12877824  aoW     1024*6*128*32*2 = 50331648   -> total 63209472
  if (ws_size < (size_t)63209472) return;
  ushort_t* wqkvP  = (ushort_t*)(ws);
  ushort_t* wfcP   = (ushort_t*)(ws + 221184);
  ushort_t* bias_p = (ushort_t*)(ws + 294912);
  ushort_t* aoW    = (ushort_t*)(ws + 12877824);

  hipLaunchKernelGGL(prep_wqkv, dim3(216), dim3(64), 0, stream, w_qkv, wqkvP);
  hipLaunchKernelGGL(prep_wfc,  dim3(72),  dim3(64), 0, stream, w_fc, wfcP);
  hipLaunchKernelGGL(prep_bias, dim3(NWIN*NH*8), dim3(512), 0, stream, rpt, mask, rpi, bias_p);

  hipLaunchKernelGGL(fused_kernel, dim3(1024), dim3(512), 0, stream,
                     x, wqkvP, b_qkv, bias_p, aoW, wfcP, b_fc, out);
}